// Round 1
// baseline (458.742 us; speedup 1.0000x reference)
//
#include <hip/hip_runtime.h>

// Problem constants: B=2, S=2048, E=1024, H=16, D=64, WIN=16
#define BB 2
#define SS 2048
#define EE 1024
#define HH 16
#define DD 64

typedef __attribute__((ext_vector_type(8))) short short8;
typedef __attribute__((ext_vector_type(4))) float f32x4;

__device__ __forceinline__ float bf2f(unsigned short u) {
  union { unsigned int i; float f; } v; v.i = ((unsigned int)u) << 16; return v.f;
}
__device__ __forceinline__ unsigned short f2bf(float f) {
  unsigned int u = __float_as_uint(f);
  u += 0x7fff + ((u >> 16) & 1);   // RNE
  return (unsigned short)(u >> 16);
}
__device__ __forceinline__ void gload_lds16(const void* g, void* l) {
  __builtin_amdgcn_global_load_lds(
      (const __attribute__((address_space(1))) void*)g,
      (__attribute__((address_space(3))) void*)l, 16, 0, 0);
}

// ---------------- f32 -> bf16 cast ----------------
__global__ void cast_f32_bf16(const float* __restrict__ in,
                              unsigned short* __restrict__ out, int n) {
  int i = (blockIdx.x * 256 + threadIdx.x) * 4;
  if (i >= n) return;
  float4 v = *reinterpret_cast<const float4*>(in + i);
  ushort4 o;
  o.x = f2bf(v.x); o.y = f2bf(v.y); o.z = f2bf(v.z); o.w = f2bf(v.w);
  *reinterpret_cast<ushort4*>(out + i) = o;
}

// ---------------- bf16 GEMM: C[M,N] = A[M,K] @ B[N,K]^T + bias ----------------
// A row-major bf16, B row-major (N,K) bf16 (i.e. B^T layout), f32 accum.
// 128x128 tile, 4 waves (2x2 of 64x64), BK=32, mfma_f32_16x16x32_bf16.
template <int OUT_BF16>
__global__ __launch_bounds__(256, 2)
void gemm_bt(const unsigned short* __restrict__ A,
             const unsigned short* __restrict__ B,
             const float* __restrict__ bias,
             void* __restrict__ C, int M, int N, int K) {
  __shared__ unsigned short As[128 * 32];
  __shared__ unsigned short Bs[128 * 32];
  const int tid = threadIdx.x;
  const int wid = tid >> 6;
  const int lane = tid & 63;
  const int tileM = blockIdx.x * 128;
  const int tileN = blockIdx.y * 128;
  const int wm = (wid >> 1) * 64;     // wave row offset in tile
  const int wn = (wid & 1) * 64;      // wave col offset in tile
  const int rl = lane & 15;           // fragment row/col within 16
  const int kc = (lane >> 4) * 8;     // fragment k offset (elements)

  f32x4 acc[4][4] = {};

  // staging map: flat byte f = tid*16 + round*4096 over [128][32] bf16 tile
  const int srow = tid >> 2;          // 0..63
  const int scol = (tid & 3) * 8;     // element column
  const unsigned short* gA = A + (size_t)(tileM + srow) * K + scol;
  const unsigned short* gB = B + (size_t)(tileN + srow) * K + scol;
  char* ldsA = (char*)As + (tid >> 6) * 1024;  // wave-uniform base
  char* ldsB = (char*)Bs + (tid >> 6) * 1024;

  for (int k0 = 0; k0 < K; k0 += 32) {
    gload_lds16(gA + k0, ldsA);
    gload_lds16(gA + (size_t)64 * K + k0, ldsA + 4096);
    gload_lds16(gB + k0, ldsB);
    gload_lds16(gB + (size_t)64 * K + k0, ldsB + 4096);
    __syncthreads();  // compiler drains vmcnt before barrier

    short8 af[4], bfg[4];
#pragma unroll
    for (int mi = 0; mi < 4; ++mi)
      af[mi] = *reinterpret_cast<const short8*>(&As[(wm + mi * 16 + rl) * 32 + kc]);
#pragma unroll
    for (int ni = 0; ni < 4; ++ni)
      bfg[ni] = *reinterpret_cast<const short8*>(&Bs[(wn + ni * 16 + rl) * 32 + kc]);
#pragma unroll
    for (int mi = 0; mi < 4; ++mi)
#pragma unroll
      for (int ni = 0; ni < 4; ++ni)
        acc[mi][ni] = __builtin_amdgcn_mfma_f32_16x16x32_bf16(
            af[mi], bfg[ni], acc[mi][ni], 0, 0, 0);
    __syncthreads();
  }

  // epilogue: C/D layout col=lane&15, row=(lane>>4)*4+reg
  const int crow0 = (lane >> 4) * 4;
  const int ccol = lane & 15;
#pragma unroll
  for (int mi = 0; mi < 4; ++mi)
#pragma unroll
    for (int ni = 0; ni < 4; ++ni) {
      int gc = tileN + wn + ni * 16 + ccol;
      float bv = bias ? bias[gc] : 0.0f;
#pragma unroll
      for (int r = 0; r < 4; ++r) {
        int gr = tileM + wm + mi * 16 + crow0 + r;
        if (gr < M) {
          float v = acc[mi][ni][r] + bv;
          if (OUT_BF16)
            ((unsigned short*)C)[(size_t)gr * N + gc] = f2bf(v);
          else
            ((float*)C)[(size_t)gr * N + gc] = v;
        }
      }
    }
}

// ---------------- tiny f32 GEMV: Y[b][n] = X[b]·W[n] + bias[n], b in {0,1} ----------------
__global__ void gemv2(const float* __restrict__ X, size_t xstride,
                      const float* __restrict__ W, const float* __restrict__ bias,
                      float* __restrict__ Y, size_t ystride, int N, int K) {
  int gw = blockIdx.x * 4 + (threadIdx.x >> 6);
  int lane = threadIdx.x & 63;
  if (gw >= 2 * N) return;
  int b = gw / N, n = gw % N;
  const float* x = X + (size_t)b * xstride;
  const float* w = W + (size_t)n * K;
  float s = 0.0f;
  for (int k = lane; k < K; k += 64) s += x[k] * w[k];
  for (int off = 32; off; off >>= 1) s += __shfl_xor(s, off);
  if (lane == 0) Y[(size_t)b * ystride + n] = s + bias[n];
}

// ---------------- global (cls) attention: q = token 0, keys = all S ----------------
__global__ __launch_bounds__(256)
void attn_global(const float* __restrict__ qcls,           // [2][1024]
                 const unsigned short* __restrict__ Ycls,  // [4096][2048] = k|v
                 float* __restrict__ ctxg) {               // [2][1024]
  int b = blockIdx.x >> 4;
  int h = blockIdx.x & 15;
  __shared__ float q[64];
  __shared__ float sc[SS];
  __shared__ float red[8];
  __shared__ float part[4][64];
  int tid = threadIdx.x;
  if (tid < 64) q[tid] = qcls[b * EE + h * DD + tid];
  __syncthreads();

  float lmax = -1e30f;
  for (int s = tid; s < SS; s += 256) {
    const unsigned short* krow = Ycls + (size_t)(b * SS + s) * 2048 + h * DD;
    float dot = 0.0f;
#pragma unroll 8
    for (int d = 0; d < DD; ++d) dot += q[d] * bf2f(krow[d]);
    dot *= 0.125f;
    sc[s] = dot;
    lmax = fmaxf(lmax, dot);
  }
  for (int off = 32; off; off >>= 1) lmax = fmaxf(lmax, __shfl_xor(lmax, off));
  if ((tid & 63) == 0) red[tid >> 6] = lmax;
  __syncthreads();
  float M = fmaxf(fmaxf(red[0], red[1]), fmaxf(red[2], red[3]));

  float lsum = 0.0f;
  for (int s = tid; s < SS; s += 256) {
    float p = __expf(sc[s] - M);
    sc[s] = p;
    lsum += p;
  }
  for (int off = 32; off; off >>= 1) lsum += __shfl_xor(lsum, off);
  if ((tid & 63) == 0) red[4 + (tid >> 6)] = lsum;
  __syncthreads();
  float Z = red[4] + red[5] + red[6] + red[7];

  int d = tid & 63, g = tid >> 6;
  float acc = 0.0f;
  for (int s = g; s < SS; s += 4)
    acc += sc[s] * bf2f(Ycls[(size_t)(b * SS + s) * 2048 + 1024 + h * DD + d]);
  part[g][d] = acc;
  __syncthreads();
  if (g == 0)
    ctxg[b * EE + h * DD + d] = (part[0][d] + part[1][d] + part[2][d] + part[3][d]) / Z;
}

// ---------------- local attention: window +-16, keys >= 1 ----------------
__global__ __launch_bounds__(256)
void attn_local(const unsigned short* __restrict__ Yloc,  // [4096][3072] = q|k|v
                unsigned short* __restrict__ CTX) {       // [4096][1024] bf16
  int m = blockIdx.x;              // b*2048 + s
  int s = m & (SS - 1), b = m >> 11;
  int tid = threadIdx.x, wid = tid >> 6, lane = tid & 63;
  if (s == 0) {  // ctx row 0 unused -> zero (keeps GEMM2 input deterministic)
    for (int i = tid; i < EE; i += 256) CTX[(size_t)m * EE + i] = 0;
    return;
  }
  __shared__ unsigned short qrow[EE];
  __shared__ float pbuf[4][34];
  for (int i = tid; i < EE; i += 256) qrow[i] = Yloc[(size_t)m * 3072 + i];
  __syncthreads();

  for (int h = wid; h < HH; h += 4) {
    int j = lane;
    int kk = s - 16 + j;
    bool valid = (j < 33) && (kk >= 1) && (kk < SS);
    int kkc = min(max(kk, 0), SS - 1);
    float score = -1e30f;
    if (valid) {
      const unsigned short* krow = Yloc + (size_t)(b * SS + kkc) * 3072 + 1024 + h * DD;
      const short8* k8 = reinterpret_cast<const short8*>(krow);
      float dot = 0.0f;
#pragma unroll
      for (int dc = 0; dc < 8; ++dc) {
        short8 kv = k8[dc];
#pragma unroll
        for (int e = 0; e < 8; ++e)
          dot += bf2f((unsigned short)qrow[h * DD + dc * 8 + e]) *
                 bf2f((unsigned short)kv[e]);
      }
      score = dot * 0.125f;
    }
    float Mx = score;
    for (int off = 32; off; off >>= 1) Mx = fmaxf(Mx, __shfl_xor(Mx, off));
    float p = valid ? __expf(score - Mx) : 0.0f;
    float Z = p;
    for (int off = 32; off; off >>= 1) Z += __shfl_xor(Z, off);
    if (j < 33) pbuf[wid][j] = p;
    // wave-private LDS: in-order DS ops, no barrier needed
    int d = lane;
    float acc = 0.0f;
#pragma unroll
    for (int jj = 0; jj < 33; ++jj) {
      int k2 = s - 16 + jj;
      int k2c = min(max(k2, 1), SS - 1);
      acc += pbuf[wid][jj] *
             bf2f(Yloc[(size_t)(b * SS + k2c) * 3072 + 2048 + h * DD + d]);
    }
    CTX[(size_t)m * EE + h * DD + d] = f2bf(acc / Z);
  }
}

extern "C" void kernel_launch(void* const* d_in, const int* in_sizes, int n_in,
                              void* d_out, int out_size, void* d_ws, size_t ws_size,
                              hipStream_t stream) {
  const float* hs        = (const float*)d_in[0];  // [2][2048][1024]
  const float* in_w_cls  = (const float*)d_in[1];  // [3072][1024]
  const float* in_b_cls  = (const float*)d_in[2];  // [3072]
  const float* out_w_cls = (const float*)d_in[3];  // [1024][1024]
  const float* out_b_cls = (const float*)d_in[4];  // [1024]
  const float* in_w_loc  = (const float*)d_in[5];
  const float* in_b_loc  = (const float*)d_in[6];
  const float* out_w_loc = (const float*)d_in[7];
  const float* out_b_loc = (const float*)d_in[8];
  float* out = (float*)d_out;                      // [2][2048][1024] f32

  const int M = BB * SS;  // 4096
  char* ws = (char*)d_ws;
  size_t off = 0;
  auto alloc = [&](size_t bytes) { char* p = ws + off; off += (bytes + 255) & ~(size_t)255; return p; };
  unsigned short* Xbf  = (unsigned short*)alloc((size_t)M * EE * 2);        // hs bf16
  unsigned short* Wckv = (unsigned short*)alloc((size_t)2048 * EE * 2);     // in_w_cls rows 1024..3071
  unsigned short* Wloc = (unsigned short*)alloc((size_t)3072 * EE * 2);     // in_w_loc
  unsigned short* Wout = (unsigned short*)alloc((size_t)EE * EE * 2);       // out_w_loc
  unsigned short* Ycls = (unsigned short*)alloc((size_t)M * 2048 * 2);      // [k|v] cls
  unsigned short* Yloc = (unsigned short*)alloc((size_t)M * 3072 * 2);      // [q|k|v] loc
  unsigned short* CTX  = (unsigned short*)alloc((size_t)M * EE * 2);        // local ctx
  float* qcls = (float*)alloc(2 * EE * 4);
  float* ctxg = (float*)alloc(2 * EE * 4);

  // 1) casts to bf16
  {
    int n;
    n = M * EE;       cast_f32_bf16<<<n / 1024, 256, 0, stream>>>(hs, Xbf, n);
    n = 2048 * EE;    cast_f32_bf16<<<n / 1024, 256, 0, stream>>>(in_w_cls + (size_t)EE * EE, Wckv, n);
    n = 3072 * EE;    cast_f32_bf16<<<n / 1024, 256, 0, stream>>>(in_w_loc, Wloc, n);
    n = EE * EE;      cast_f32_bf16<<<n / 1024, 256, 0, stream>>>(out_w_loc, Wout, n);
  }

  // 2) q_cls (2 rows, f32)
  gemv2<<<512, 256, 0, stream>>>(hs, (size_t)SS * EE, in_w_cls, in_b_cls,
                                 qcls, EE, EE, EE);

  // 3) projections (bf16 MFMA GEMMs, bias fused)
  {
    dim3 g1(M / 128, 2048 / 128);
    gemm_bt<1><<<g1, 256, 0, stream>>>(Xbf, Wckv, in_b_cls + EE, Ycls, M, 2048, EE);
    dim3 g2(M / 128, 3072 / 128);
    gemm_bt<1><<<g2, 256, 0, stream>>>(Xbf, Wloc, in_b_loc, Yloc, M, 3072, EE);
  }

  // 4) attention
  attn_global<<<BB * HH, 256, 0, stream>>>(qcls, Ycls, ctxg);
  attn_local<<<M, 256, 0, stream>>>(Yloc, CTX);

  // 5) local output projection -> writes all 4096 rows of d_out (rows 0,2048 garbage)
  {
    dim3 g3(M / 128, EE / 128);
    gemm_bt<0><<<g3, 256, 0, stream>>>(CTX, Wout, out_b_loc, out, M, EE, EE);
  }

  // 6) cls output rows (overwrite rows b*2048)
  gemv2<<<512, 256, 0, stream>>>(ctxg, EE, out_w_cls, out_b_cls,
                                 out, (size_t)SS * EE, EE, EE);
}

// Round 2
// 216.306 us; speedup vs baseline: 2.1208x; 2.1208x over previous
//
#include <hip/hip_runtime.h>

// Problem constants: B=2, S=2048, E=1024, H=16, D=64, WIN=16
#define BB 2
#define SS 2048
#define EE 1024
#define HH 16
#define DD 64

typedef __attribute__((ext_vector_type(8))) short short8;
typedef __attribute__((ext_vector_type(4))) short short4v;
typedef __attribute__((ext_vector_type(4))) float f32x4;

__device__ __forceinline__ float bf2f(unsigned short u) {
  union { unsigned int i; float f; } v; v.i = ((unsigned int)u) << 16; return v.f;
}
__device__ __forceinline__ unsigned short f2bf(float f) {
  unsigned int u = __float_as_uint(f);
  u += 0x7fff + ((u >> 16) & 1);   // RNE
  return (unsigned short)(u >> 16);
}
__device__ __forceinline__ void gload_lds16(const void* g, void* l) {
  __builtin_amdgcn_global_load_lds(
      (const __attribute__((address_space(1))) void*)g,
      (__attribute__((address_space(3))) void*)l, 16, 0, 0);
}

// ---------------- f32 -> bf16 cast ----------------
__global__ void cast_f32_bf16(const float* __restrict__ in,
                              unsigned short* __restrict__ out, int n) {
  int i = (blockIdx.x * 256 + threadIdx.x) * 4;
  if (i >= n) return;
  float4 v = *reinterpret_cast<const float4*>(in + i);
  ushort4 o;
  o.x = f2bf(v.x); o.y = f2bf(v.y); o.z = f2bf(v.z); o.w = f2bf(v.w);
  *reinterpret_cast<ushort4*>(out + i) = o;
}

// ---------------- bf16 GEMM: C[M,N] = A[M,K] @ B[N,K]^T + bias ----------------
// 128x128 tile, 4 waves (2x2 of 64x64), BK=32, mfma_f32_16x16x32_bf16.
template <int OUT_BF16>
__global__ __launch_bounds__(256, 2)
void gemm_bt(const unsigned short* __restrict__ A,
             const unsigned short* __restrict__ B,
             const float* __restrict__ bias,
             void* __restrict__ C, int M, int N, int K) {
  __shared__ unsigned short As[128 * 32];
  __shared__ unsigned short Bs[128 * 32];
  const int tid = threadIdx.x;
  const int wid = tid >> 6;
  const int lane = tid & 63;
  const int tileM = blockIdx.x * 128;
  const int tileN = blockIdx.y * 128;
  const int wm = (wid >> 1) * 64;
  const int wn = (wid & 1) * 64;
  const int rl = lane & 15;
  const int kc = (lane >> 4) * 8;

  f32x4 acc[4][4] = {};

  const int srow = tid >> 2;
  const int scol = (tid & 3) * 8;
  const unsigned short* gA = A + (size_t)(tileM + srow) * K + scol;
  const unsigned short* gB = B + (size_t)(tileN + srow) * K + scol;
  char* ldsA = (char*)As + (tid >> 6) * 1024;
  char* ldsB = (char*)Bs + (tid >> 6) * 1024;

  for (int k0 = 0; k0 < K; k0 += 32) {
    gload_lds16(gA + k0, ldsA);
    gload_lds16(gA + (size_t)64 * K + k0, ldsA + 4096);
    gload_lds16(gB + k0, ldsB);
    gload_lds16(gB + (size_t)64 * K + k0, ldsB + 4096);
    __syncthreads();

    short8 af[4], bfg[4];
#pragma unroll
    for (int mi = 0; mi < 4; ++mi)
      af[mi] = *reinterpret_cast<const short8*>(&As[(wm + mi * 16 + rl) * 32 + kc]);
#pragma unroll
    for (int ni = 0; ni < 4; ++ni)
      bfg[ni] = *reinterpret_cast<const short8*>(&Bs[(wn + ni * 16 + rl) * 32 + kc]);
#pragma unroll
    for (int mi = 0; mi < 4; ++mi)
#pragma unroll
      for (int ni = 0; ni < 4; ++ni)
        acc[mi][ni] = __builtin_amdgcn_mfma_f32_16x16x32_bf16(
            af[mi], bfg[ni], acc[mi][ni], 0, 0, 0);
    __syncthreads();
  }

  const int crow0 = (lane >> 4) * 4;
  const int ccol = lane & 15;
#pragma unroll
  for (int mi = 0; mi < 4; ++mi)
#pragma unroll
    for (int ni = 0; ni < 4; ++ni) {
      int gc = tileN + wn + ni * 16 + ccol;
      float bv = bias ? bias[gc] : 0.0f;
#pragma unroll
      for (int r = 0; r < 4; ++r) {
        int gr = tileM + wm + mi * 16 + crow0 + r;
        if (gr < M) {
          float v = acc[mi][ni][r] + bv;
          if (OUT_BF16)
            ((unsigned short*)C)[(size_t)gr * N + gc] = f2bf(v);
          else
            ((float*)C)[(size_t)gr * N + gc] = v;
        }
      }
    }
}

// ---------------- tiny f32 GEMV: Y[b][n] = X[b]·W[n] + bias[n], b in {0,1} ----------------
__global__ void gemv2(const float* __restrict__ X, size_t xstride,
                      const float* __restrict__ W, const float* __restrict__ bias,
                      float* __restrict__ Y, size_t ystride, int N, int K) {
  int gw = blockIdx.x * 4 + (threadIdx.x >> 6);
  int lane = threadIdx.x & 63;
  if (gw >= 2 * N) return;
  int b = gw / N, n = gw % N;
  const float* x = X + (size_t)b * xstride;
  const float* w = W + (size_t)n * K;
  float s = 0.0f;
  for (int k = lane; k < K; k += 64) s += x[k] * w[k];
  for (int off = 32; off; off >>= 1) s += __shfl_xor(s, off);
  if (lane == 0) Y[(size_t)b * ystride + n] = s + bias[n];
}

// ---------------- global (cls) attention, phase A: partial per key-chunk ----------------
// grid (8,16,2): kc, h, b. part layout [b][h][kc][66]: m, l, acc[64] (unnormalized)
__global__ __launch_bounds__(256)
void attn_gpart(const float* __restrict__ qcls,
                const unsigned short* __restrict__ Ycls,
                float* __restrict__ part) {
  int kc = blockIdx.x, h = blockIdx.y, b = blockIdx.z;
  int tid = threadIdx.x;
  __shared__ float qf[64];
  __shared__ float ps[256];
  __shared__ float red[8];
  __shared__ float pacc[4][64];
  if (tid < 64) qf[tid] = qcls[b * EE + h * DD + tid];
  __syncthreads();

  int s = kc * 256 + tid;
  const short8* k8 = (const short8*)(Ycls + (size_t)(b * SS + s) * 2048 + h * DD);
  float dot = 0.0f;
#pragma unroll
  for (int i = 0; i < 8; ++i) {
    short8 kv = k8[i];
#pragma unroll
    for (int e = 0; e < 8; ++e) dot += qf[i * 8 + e] * bf2f((unsigned short)kv[e]);
  }
  dot *= 0.125f;

  float mx = dot;
  for (int o = 32; o; o >>= 1) mx = fmaxf(mx, __shfl_xor(mx, o));
  if ((tid & 63) == 0) red[tid >> 6] = mx;
  __syncthreads();
  float M = fmaxf(fmaxf(red[0], red[1]), fmaxf(red[2], red[3]));

  float p = __expf(dot - M);
  ps[tid] = p;
  float l = p;
  for (int o = 32; o; o >>= 1) l += __shfl_xor(l, o);
  if ((tid & 63) == 0) red[4 + (tid >> 6)] = l;
  __syncthreads();
  float L = red[4] + red[5] + red[6] + red[7];

  int g = tid >> 6, d = tid & 63;
  float acc = 0.0f;
  for (int sl = g; sl < 256; sl += 4)
    acc += ps[sl] * bf2f(Ycls[(size_t)(b * SS + kc * 256 + sl) * 2048 + 1024 + h * DD + d]);
  pacc[g][d] = acc;
  __syncthreads();
  if (g == 0) {
    float a = pacc[0][d] + pacc[1][d] + pacc[2][d] + pacc[3][d];
    float* pp = part + ((size_t)(b * HH + h) * 8 + kc) * 66;
    if (d == 0) { pp[0] = M; pp[1] = L; }
    pp[2 + d] = a;
  }
}

// phase B: combine 8 chunks. grid 32 blocks (b*16+h), 64 threads.
__global__ void attn_gcomb(const float* __restrict__ part, float* __restrict__ ctxg) {
  int bh = blockIdx.x, d = threadIdx.x;
  const float* pp = part + (size_t)bh * 8 * 66;
  float M = -1e30f;
#pragma unroll
  for (int i = 0; i < 8; ++i) M = fmaxf(M, pp[i * 66]);
  float Z = 0.0f, a = 0.0f;
#pragma unroll
  for (int i = 0; i < 8; ++i) {
    float w = __expf(pp[i * 66] - M);
    Z += w * pp[i * 66 + 1];
    a += w * pp[i * 66 + 2 + d];
  }
  int b = bh >> 4, h = bh & 15;
  ctxg[b * EE + h * DD + d] = a / Z;
}

// ---------------- local attention: window +-16, keys >= 1 ----------------
// grid (16,16,2): chunk of 128 queries, head, batch. K/V window staged in LDS.
#define QB 128
#define KW 160
#define KP 68   // padded LDS row (rows start 2 banks apart -> <=2-way conflicts)
__global__ __launch_bounds__(256, 2)
void attn_local(const unsigned short* __restrict__ Yloc,  // [4096][3072] = q|k|v
                unsigned short* __restrict__ CTX) {       // [4096][1024] bf16
  const int c = blockIdx.x, h = blockIdx.y, b = blockIdx.z;
  const int s0 = c * QB;
  const int tid = threadIdx.x, wid = tid >> 6, lane = tid & 63;
  __shared__ unsigned short Qs[QB][DD];
  __shared__ unsigned short Ks[KW][KP];
  __shared__ unsigned short Vs[KW][KP];
  __shared__ float pb[4][36];

  // stage Q (128x64)
  {
    const size_t base = (size_t)(b * SS + s0) * 3072 + h * DD;
#pragma unroll
    for (int i = 0; i < 4; ++i) {
      int flat = (i * 256 + tid) * 8;
      int row = flat >> 6, col = flat & 63;
      short8 v = *(const short8*)&Yloc[base + (size_t)row * 3072 + col];
      *(short8*)&Qs[row][col] = v;
    }
    // stage K,V windows (160x64), rows clamped (mask handles edges)
#pragma unroll
    for (int i = 0; i < 5; ++i) {
      int flat = (i * 256 + tid) * 8;
      int row = flat >> 6, col = flat & 63;
      int gr = min(max(s0 - 16 + row, 0), SS - 1);
      const size_t rb = (size_t)(b * SS + gr) * 3072 + h * DD;
      short8 kv = *(const short8*)&Yloc[rb + 1024 + col];
      short8 vv = *(const short8*)&Yloc[rb + 2048 + col];
      *(short4v*)&Ks[row][col]     = __builtin_shufflevector(kv, kv, 0, 1, 2, 3);
      *(short4v*)&Ks[row][col + 4] = __builtin_shufflevector(kv, kv, 4, 5, 6, 7);
      *(short4v*)&Vs[row][col]     = __builtin_shufflevector(vv, vv, 0, 1, 2, 3);
      *(short4v*)&Vs[row][col + 4] = __builtin_shufflevector(vv, vv, 4, 5, 6, 7);
    }
  }
  __syncthreads();

  // each wave owns 32 consecutive queries
  for (int qi = 0; qi < 32; ++qi) {
    const int q_l = wid * 32 + qi;
    const int sg = s0 + q_l;
    const int d = lane;
    if (sg == 0) {  // ctx row 0 unused by reference -> zero this head's slice
      CTX[(size_t)(b * SS) * EE + h * DD + d] = 0;
      continue;
    }
    const int j = lane;
    const int kk = sg - 16 + j;
    const bool valid = (j < 33) && (kk >= 1) && (kk < SS);
    float score = -1e30f;
    if (valid) {
      const short8* q8 = (const short8*)&Qs[q_l][0];
      const short4v* kr = (const short4v*)&Ks[q_l + j][0];
      float dot = 0.0f;
#pragma unroll
      for (int i = 0; i < 8; ++i) {
        short8 qv = q8[i];
        short4v k0 = kr[2 * i], k1 = kr[2 * i + 1];
#pragma unroll
        for (int e = 0; e < 4; ++e) {
          dot += bf2f((unsigned short)qv[e]) * bf2f((unsigned short)k0[e]);
          dot += bf2f((unsigned short)qv[4 + e]) * bf2f((unsigned short)k1[e]);
        }
      }
      score = dot * 0.125f;
    }
    float M = score;
    for (int o = 32; o; o >>= 1) M = fmaxf(M, __shfl_xor(M, o));
    float p = valid ? __expf(score - M) : 0.0f;
    float Z = p;
    for (int o = 32; o; o >>= 1) Z += __shfl_xor(Z, o);
    if (j < 33) pb[wid][j] = p;
    // wave-private LDS buffer: compiler orders ds ops via lgkmcnt
    float acc = 0.0f;
#pragma unroll
    for (int jj = 0; jj < 33; ++jj)
      acc += pb[wid][jj] * bf2f((unsigned short)Vs[q_l + jj][d]);
    CTX[(size_t)(b * SS + sg) * EE + h * DD + d] = f2bf(acc / Z);
  }
}

extern "C" void kernel_launch(void* const* d_in, const int* in_sizes, int n_in,
                              void* d_out, int out_size, void* d_ws, size_t ws_size,
                              hipStream_t stream) {
  const float* hs        = (const float*)d_in[0];
  const float* in_w_cls  = (const float*)d_in[1];
  const float* in_b_cls  = (const float*)d_in[2];
  const float* out_w_cls = (const float*)d_in[3];
  const float* out_b_cls = (const float*)d_in[4];
  const float* in_w_loc  = (const float*)d_in[5];
  const float* in_b_loc  = (const float*)d_in[6];
  const float* out_w_loc = (const float*)d_in[7];
  const float* out_b_loc = (const float*)d_in[8];
  float* out = (float*)d_out;

  const int M = BB * SS;  // 4096
  char* ws = (char*)d_ws;
  size_t off = 0;
  auto alloc = [&](size_t bytes) { char* p = ws + off; off += (bytes + 255) & ~(size_t)255; return p; };
  unsigned short* Xbf  = (unsigned short*)alloc((size_t)M * EE * 2);
  unsigned short* Wckv = (unsigned short*)alloc((size_t)2048 * EE * 2);
  unsigned short* Wloc = (unsigned short*)alloc((size_t)3072 * EE * 2);
  unsigned short* Wout = (unsigned short*)alloc((size_t)EE * EE * 2);
  unsigned short* Ycls = (unsigned short*)alloc((size_t)M * 2048 * 2);
  unsigned short* Yloc = (unsigned short*)alloc((size_t)M * 3072 * 2);
  unsigned short* CTX  = (unsigned short*)alloc((size_t)M * EE * 2);
  float* qcls = (float*)alloc(2 * EE * 4);
  float* ctxg = (float*)alloc(2 * EE * 4);
  float* part = (float*)alloc((size_t)BB * HH * 8 * 66 * 4);

  // 1) casts to bf16
  {
    int n;
    n = M * EE;       cast_f32_bf16<<<n / 1024, 256, 0, stream>>>(hs, Xbf, n);
    n = 2048 * EE;    cast_f32_bf16<<<n / 1024, 256, 0, stream>>>(in_w_cls + (size_t)EE * EE, Wckv, n);
    n = 3072 * EE;    cast_f32_bf16<<<n / 1024, 256, 0, stream>>>(in_w_loc, Wloc, n);
    n = EE * EE;      cast_f32_bf16<<<n / 1024, 256, 0, stream>>>(out_w_loc, Wout, n);
  }

  // 2) q_cls (2 rows, f32)
  gemv2<<<512, 256, 0, stream>>>(hs, (size_t)SS * EE, in_w_cls, in_b_cls,
                                 qcls, EE, EE, EE);

  // 3) projections (bf16 MFMA GEMMs, bias fused)
  {
    dim3 g1(M / 128, 2048 / 128);
    gemm_bt<1><<<g1, 256, 0, stream>>>(Xbf, Wckv, in_b_cls + EE, Ycls, M, 2048, EE);
    dim3 g2(M / 128, 3072 / 128);
    gemm_bt<1><<<g2, 256, 0, stream>>>(Xbf, Wloc, in_b_loc, Yloc, M, 3072, EE);
  }

  // 4) attention
  attn_gpart<<<dim3(8, HH, BB), 256, 0, stream>>>(qcls, Ycls, part);
  attn_gcomb<<<BB * HH, 64, 0, stream>>>(part, ctxg);
  attn_local<<<dim3(SS / QB, HH, BB), 256, 0, stream>>>(Yloc, CTX);

  // 5) local output projection -> all 4096 rows of d_out (rows 0,2048 overwritten next)
  {
    dim3 g3(M / 128, EE / 128);
    gemm_bt<0><<<g3, 256, 0, stream>>>(CTX, Wout, out_b_loc, out, M, EE, EE);
  }

  // 6) cls output rows
  gemv2<<<512, 256, 0, stream>>>(ctxg, EE, out_w_cls, out_b_cls,
                                 out, (size_t)SS * EE, EE, EE);
}

// Round 3
// 172.201 us; speedup vs baseline: 2.6640x; 1.2561x over previous
//
#include <hip/hip_runtime.h>

// Problem constants: B=2, S=2048, E=1024, H=16, D=64, WIN=16
#define BB 2
#define SS 2048
#define EE 1024
#define HH 16
#define DD 64

typedef __attribute__((ext_vector_type(8))) short short8;
typedef __attribute__((ext_vector_type(4))) float f32x4;

__device__ __forceinline__ float bf2f(unsigned short u) {
  union { unsigned int i; float f; } v; v.i = ((unsigned int)u) << 16; return v.f;
}
__device__ __forceinline__ unsigned short f2bf(float f) {
  unsigned int u = __float_as_uint(f);
  u += 0x7fff + ((u >> 16) & 1);   // RNE
  return (unsigned short)(u >> 16);
}
__device__ __forceinline__ void gload_lds16(const void* g, void* l) {
  __builtin_amdgcn_global_load_lds(
      (const __attribute__((address_space(1))) void*)g,
      (__attribute__((address_space(3))) void*)l, 16, 0, 0);
}

// ---------------- f32 -> bf16 cast ----------------
__global__ void cast_f32_bf16(const float* __restrict__ in,
                              unsigned short* __restrict__ out, int n) {
  int i = (blockIdx.x * 256 + threadIdx.x) * 4;
  if (i >= n) return;
  float4 v = *reinterpret_cast<const float4*>(in + i);
  ushort4 o;
  o.x = f2bf(v.x); o.y = f2bf(v.y); o.z = f2bf(v.z); o.w = f2bf(v.w);
  *reinterpret_cast<ushort4*>(out + i) = o;
}

// ---------------- bf16 GEMM: C[M,N] = A[M,K] @ B[N,K]^T + bias ----------------
// 128x128 tile, 4 waves (2x2 of 64x64), BK=32, mfma_f32_16x16x32_bf16.
template <int OUT_BF16>
__global__ __launch_bounds__(256, 2)
void gemm_bt(const unsigned short* __restrict__ A,
             const unsigned short* __restrict__ B,
             const float* __restrict__ bias,
             void* __restrict__ C, int M, int N, int K) {
  __shared__ unsigned short As[128 * 32];
  __shared__ unsigned short Bs[128 * 32];
  const int tid = threadIdx.x;
  const int wid = tid >> 6;
  const int lane = tid & 63;
  const int tileM = blockIdx.x * 128;
  const int tileN = blockIdx.y * 128;
  const int wm = (wid >> 1) * 64;
  const int wn = (wid & 1) * 64;
  const int rl = lane & 15;
  const int kc = (lane >> 4) * 8;

  f32x4 acc[4][4] = {};

  const int srow = tid >> 2;
  const int scol = (tid & 3) * 8;
  const unsigned short* gA = A + (size_t)(tileM + srow) * K + scol;
  const unsigned short* gB = B + (size_t)(tileN + srow) * K + scol;
  char* ldsA = (char*)As + (tid >> 6) * 1024;
  char* ldsB = (char*)Bs + (tid >> 6) * 1024;

  for (int k0 = 0; k0 < K; k0 += 32) {
    gload_lds16(gA + k0, ldsA);
    gload_lds16(gA + (size_t)64 * K + k0, ldsA + 4096);
    gload_lds16(gB + k0, ldsB);
    gload_lds16(gB + (size_t)64 * K + k0, ldsB + 4096);
    __syncthreads();

    short8 af[4], bfg[4];
#pragma unroll
    for (int mi = 0; mi < 4; ++mi)
      af[mi] = *reinterpret_cast<const short8*>(&As[(wm + mi * 16 + rl) * 32 + kc]);
#pragma unroll
    for (int ni = 0; ni < 4; ++ni)
      bfg[ni] = *reinterpret_cast<const short8*>(&Bs[(wn + ni * 16 + rl) * 32 + kc]);
#pragma unroll
    for (int mi = 0; mi < 4; ++mi)
#pragma unroll
      for (int ni = 0; ni < 4; ++ni)
        acc[mi][ni] = __builtin_amdgcn_mfma_f32_16x16x32_bf16(
            af[mi], bfg[ni], acc[mi][ni], 0, 0, 0);
    __syncthreads();
  }

  const int crow0 = (lane >> 4) * 4;
  const int ccol = lane & 15;
#pragma unroll
  for (int mi = 0; mi < 4; ++mi)
#pragma unroll
    for (int ni = 0; ni < 4; ++ni) {
      int gc = tileN + wn + ni * 16 + ccol;
      float bv = bias ? bias[gc] : 0.0f;
#pragma unroll
      for (int r = 0; r < 4; ++r) {
        int gr = tileM + wm + mi * 16 + crow0 + r;
        if (gr < M) {
          float v = acc[mi][ni][r] + bv;
          if (OUT_BF16)
            ((unsigned short*)C)[(size_t)gr * N + gc] = f2bf(v);
          else
            ((float*)C)[(size_t)gr * N + gc] = v;
        }
      }
    }
}

// ---------------- tiny f32 GEMV: Y[b][n] = X[b]·W[n] + bias[n], b in {0,1} ----------------
__global__ void gemv2(const float* __restrict__ X, size_t xstride,
                      const float* __restrict__ W, const float* __restrict__ bias,
                      float* __restrict__ Y, size_t ystride, int N, int K) {
  int gw = blockIdx.x * 4 + (threadIdx.x >> 6);
  int lane = threadIdx.x & 63;
  if (gw >= 2 * N) return;
  int b = gw / N, n = gw % N;
  const float* x = X + (size_t)b * xstride;
  const float* w = W + (size_t)n * K;
  float s = 0.0f;
  for (int k = lane; k < K; k += 64) s += x[k] * w[k];
  for (int off = 32; off; off >>= 1) s += __shfl_xor(s, off);
  if (lane == 0) Y[(size_t)b * ystride + n] = s + bias[n];
}

// ---------------- global (cls) attention, phase A: partial per key-chunk ----------------
__global__ __launch_bounds__(256)
void attn_gpart(const float* __restrict__ qcls,
                const unsigned short* __restrict__ Ycls,
                float* __restrict__ part) {
  int kc = blockIdx.x, h = blockIdx.y, b = blockIdx.z;
  int tid = threadIdx.x;
  __shared__ float qf[64];
  __shared__ float ps[256];
  __shared__ float red[8];
  __shared__ float pacc[4][64];
  if (tid < 64) qf[tid] = qcls[b * EE + h * DD + tid];
  __syncthreads();

  int s = kc * 256 + tid;
  const short8* k8 = (const short8*)(Ycls + (size_t)(b * SS + s) * 2048 + h * DD);
  float dot = 0.0f;
#pragma unroll
  for (int i = 0; i < 8; ++i) {
    short8 kv = k8[i];
#pragma unroll
    for (int e = 0; e < 8; ++e) dot += qf[i * 8 + e] * bf2f((unsigned short)kv[e]);
  }
  dot *= 0.125f;

  float mx = dot;
  for (int o = 32; o; o >>= 1) mx = fmaxf(mx, __shfl_xor(mx, o));
  if ((tid & 63) == 0) red[tid >> 6] = mx;
  __syncthreads();
  float M = fmaxf(fmaxf(red[0], red[1]), fmaxf(red[2], red[3]));

  float p = __expf(dot - M);
  ps[tid] = p;
  float l = p;
  for (int o = 32; o; o >>= 1) l += __shfl_xor(l, o);
  if ((tid & 63) == 0) red[4 + (tid >> 6)] = l;
  __syncthreads();
  float L = red[4] + red[5] + red[6] + red[7];

  int g = tid >> 6, d = tid & 63;
  float acc = 0.0f;
  for (int sl = g; sl < 256; sl += 4)
    acc += ps[sl] * bf2f(Ycls[(size_t)(b * SS + kc * 256 + sl) * 2048 + 1024 + h * DD + d]);
  pacc[g][d] = acc;
  __syncthreads();
  if (g == 0) {
    float a = pacc[0][d] + pacc[1][d] + pacc[2][d] + pacc[3][d];
    float* pp = part + ((size_t)(b * HH + h) * 8 + kc) * 66;
    if (d == 0) { pp[0] = M; pp[1] = L; }
    pp[2 + d] = a;
  }
}

// phase B: combine 8 chunks.
__global__ void attn_gcomb(const float* __restrict__ part, float* __restrict__ ctxg) {
  int bh = blockIdx.x, d = threadIdx.x;
  const float* pp = part + (size_t)bh * 8 * 66;
  float M = -1e30f;
#pragma unroll
  for (int i = 0; i < 8; ++i) M = fmaxf(M, pp[i * 66]);
  float Z = 0.0f, a = 0.0f;
#pragma unroll
  for (int i = 0; i < 8; ++i) {
    float w = __expf(pp[i * 66] - M);
    Z += w * pp[i * 66 + 1];
    a += w * pp[i * 66 + 2 + d];
  }
  int b = bh >> 4, h = bh & 15;
  ctxg[b * EE + h * DD + d] = a / Z;
}

// ---------------- local attention via MFMA ----------------
// grid (16,16,2): 128-query chunk, head, batch. 4 waves, each 32 queries x 64-key window.
// S^T = K_win @ Q^T (16 mfma), softmax in-register, ctx^T = V^T @ P^T (16 mfma).
#define QBL 128
#define VT_PAD 168
#define P_PAD 72
__global__ __launch_bounds__(256, 2)
void attn_local(const unsigned short* __restrict__ Yloc,  // [4096][3072] = q|k|v
                unsigned short* __restrict__ CTX) {       // [4096][1024] bf16
  const int c = blockIdx.x, h = blockIdx.y, b = blockIdx.z;
  const int s0 = c * QBL;
  const int tid = threadIdx.x, wid = tid >> 6, lane = tid & 63;
  const int rl = lane & 15, g = lane >> 4;

  __shared__ unsigned short Vt[64][VT_PAD];     // V^T of key window [s0-16, s0+143]
  __shared__ unsigned short Pl[4][32][P_PAD];   // per-wave P (q x key)

  // stage V^T: task = chunk(8) x keypair(80); pack 2 keys per b32 write
  for (int task = tid; task < 640; task += 256) {
    int kp = task % 80, ch = task / 80;
    int k0 = kp * 2;
    int kg0 = min(max(s0 - 16 + k0, 0), SS - 1);
    int kg1 = min(max(s0 - 16 + k0 + 1, 0), SS - 1);
    short8 a = *(const short8*)&Yloc[(size_t)(b * SS + kg0) * 3072 + 2048 + h * DD + ch * 8];
    short8 bv = *(const short8*)&Yloc[(size_t)(b * SS + kg1) * 3072 + 2048 + h * DD + ch * 8];
#pragma unroll
    for (int e = 0; e < 8; ++e) {
      unsigned int w = (unsigned int)(unsigned short)a[e] |
                       ((unsigned int)(unsigned short)bv[e] << 16);
      *(unsigned int*)&Vt[ch * 8 + e][k0] = w;
    }
  }
  __syncthreads();

  const int qb = s0 + wid * 32;   // wave's first query (token index)
  const int kb = qb - 16;         // wave's first key

  // K fragments (A: row=key=rl within tile, k contiguous at g*8)
  short8 ak[4][2];
#pragma unroll
  for (int kt = 0; kt < 4; ++kt) {
    int kg = min(max(kb + kt * 16 + rl, 0), SS - 1);
    const unsigned short* kr = &Yloc[(size_t)(b * SS + kg) * 3072 + 1024 + h * DD + g * 8];
#pragma unroll
    for (int ks = 0; ks < 2; ++ks) ak[kt][ks] = *(const short8*)(kr + ks * 32);
  }
  // Q fragments (B: col=q=rl within tile, k contiguous at g*8)
  short8 bq[2][2];
#pragma unroll
  for (int cc = 0; cc < 2; ++cc) {
    const unsigned short* qr = &Yloc[(size_t)(b * SS + qb + cc * 16 + rl) * 3072 + h * DD + g * 8];
#pragma unroll
    for (int ks = 0; ks < 2; ++ks) bq[cc][ks] = *(const short8*)(qr + ks * 32);
  }

  // S^T[key][q]
  f32x4 accs[4][2] = {};
#pragma unroll
  for (int kt = 0; kt < 4; ++kt)
#pragma unroll
    for (int cc = 0; cc < 2; ++cc)
#pragma unroll
      for (int ks = 0; ks < 2; ++ks)
        accs[kt][cc] = __builtin_amdgcn_mfma_f32_16x16x32_bf16(
            ak[kt][ks], bq[cc][ks], accs[kt][cc], 0, 0, 0);

  // mask (|k-q|<=16, 1<=k<S) + row max
  float mrow[2] = {-3e38f, -3e38f};
#pragma unroll
  for (int kt = 0; kt < 4; ++kt)
#pragma unroll
    for (int cc = 0; cc < 2; ++cc)
#pragma unroll
      for (int r = 0; r < 4; ++r) {
        int kg = kb + kt * 16 + 4 * g + r;       // C row = (lane>>4)*4+reg
        int qg = qb + cc * 16 + rl;              // C col = lane&15
        bool valid = (kg >= qg - 16) && (kg <= qg + 16) && (kg >= 1) && (kg < SS);
        float v = valid ? accs[kt][cc][r] : -3e38f;
        accs[kt][cc][r] = v;
        mrow[cc] = fmaxf(mrow[cc], v);
      }
#pragma unroll
  for (int cc = 0; cc < 2; ++cc) {
    float m = mrow[cc];
    m = fmaxf(m, __shfl_xor(m, 16));
    m = fmaxf(m, __shfl_xor(m, 32));
    mrow[cc] = m;
  }

  // p = exp(0.125*(s-m)), write bf16 P to wave-private LDS, accumulate Z
  float zrow[2] = {0.0f, 0.0f};
#pragma unroll
  for (int cc = 0; cc < 2; ++cc)
#pragma unroll
    for (int kt = 0; kt < 4; ++kt) {
      ushort4 pw;
#pragma unroll
      for (int r = 0; r < 4; ++r) {
        float p = __expf((accs[kt][cc][r] - mrow[cc]) * 0.125f);
        zrow[cc] += p;
        ((unsigned short*)&pw)[r] = f2bf(p);
      }
      *(ushort4*)&Pl[wid][cc * 16 + rl][kt * 16 + 4 * g] = pw;
    }
#pragma unroll
  for (int cc = 0; cc < 2; ++cc) {
    float z = zrow[cc];
    z += __shfl_xor(z, 16);
    z += __shfl_xor(z, 32);
    zrow[cc] = 1.0f / z;
  }

  // ctx^T[d][q] = V^T @ P^T
  f32x4 accp[4][2] = {};
#pragma unroll
  for (int ks = 0; ks < 2; ++ks) {
    short8 bp[2];
#pragma unroll
    for (int cc = 0; cc < 2; ++cc)
      bp[cc] = *(const short8*)&Pl[wid][cc * 16 + rl][ks * 32 + g * 8];
#pragma unroll
    for (int mt = 0; mt < 4; ++mt) {
      short8 av = *(const short8*)&Vt[mt * 16 + rl][wid * 32 + ks * 32 + g * 8];
#pragma unroll
      for (int cc = 0; cc < 2; ++cc)
        accp[mt][cc] = __builtin_amdgcn_mfma_f32_16x16x32_bf16(
            av, bp[cc], accp[mt][cc], 0, 0, 0);
    }
  }

  // write ctx: token = qb+16cc+rl, d = 16mt + 4g + r (4 consecutive -> 8B store)
#pragma unroll
  for (int mt = 0; mt < 4; ++mt)
#pragma unroll
    for (int cc = 0; cc < 2; ++cc) {
      int token = qb + cc * 16 + rl;
      ushort4 o;
#pragma unroll
      for (int r = 0; r < 4; ++r)
        ((unsigned short*)&o)[r] = f2bf(accp[mt][cc][r] * zrow[cc]);
      *(ushort4*)&CTX[(size_t)(b * SS + token) * EE + h * DD + mt * 16 + 4 * g] = o;
    }
}

extern "C" void kernel_launch(void* const* d_in, const int* in_sizes, int n_in,
                              void* d_out, int out_size, void* d_ws, size_t ws_size,
                              hipStream_t stream) {
  const float* hs        = (const float*)d_in[0];
  const float* in_w_cls  = (const float*)d_in[1];
  const float* in_b_cls  = (const float*)d_in[2];
  const float* out_w_cls = (const float*)d_in[3];
  const float* out_b_cls = (const float*)d_in[4];
  const float* in_w_loc  = (const float*)d_in[5];
  const float* in_b_loc  = (const float*)d_in[6];
  const float* out_w_loc = (const float*)d_in[7];
  const float* out_b_loc = (const float*)d_in[8];
  float* out = (float*)d_out;

  const int M = BB * SS;  // 4096
  char* ws = (char*)d_ws;
  size_t off = 0;
  auto alloc = [&](size_t bytes) { char* p = ws + off; off += (bytes + 255) & ~(size_t)255; return p; };
  unsigned short* Xbf  = (unsigned short*)alloc((size_t)M * EE * 2);
  unsigned short* Wckv = (unsigned short*)alloc((size_t)2048 * EE * 2);
  unsigned short* Wloc = (unsigned short*)alloc((size_t)3072 * EE * 2);
  unsigned short* Wout = (unsigned short*)alloc((size_t)EE * EE * 2);
  unsigned short* Ycls = (unsigned short*)alloc((size_t)M * 2048 * 2);
  unsigned short* Yloc = (unsigned short*)alloc((size_t)M * 3072 * 2);
  unsigned short* CTX  = (unsigned short*)alloc((size_t)M * EE * 2);
  float* qcls = (float*)alloc(2 * EE * 4);
  float* ctxg = (float*)alloc(2 * EE * 4);
  float* part = (float*)alloc((size_t)BB * HH * 8 * 66 * 4);

  // 1) casts to bf16
  {
    int n;
    n = M * EE;       cast_f32_bf16<<<n / 1024, 256, 0, stream>>>(hs, Xbf, n);
    n = 2048 * EE;    cast_f32_bf16<<<n / 1024, 256, 0, stream>>>(in_w_cls + (size_t)EE * EE, Wckv, n);
    n = 3072 * EE;    cast_f32_bf16<<<n / 1024, 256, 0, stream>>>(in_w_loc, Wloc, n);
    n = EE * EE;      cast_f32_bf16<<<n / 1024, 256, 0, stream>>>(out_w_loc, Wout, n);
  }

  // 2) q_cls (2 rows, f32)
  gemv2<<<512, 256, 0, stream>>>(hs, (size_t)SS * EE, in_w_cls, in_b_cls,
                                 qcls, EE, EE, EE);

  // 3) projections (bf16 MFMA GEMMs, bias fused)
  {
    dim3 g1(M / 128, 2048 / 128);
    gemm_bt<1><<<g1, 256, 0, stream>>>(Xbf, Wckv, in_b_cls + EE, Ycls, M, 2048, EE);
    dim3 g2(M / 128, 3072 / 128);
    gemm_bt<1><<<g2, 256, 0, stream>>>(Xbf, Wloc, in_b_loc, Yloc, M, 3072, EE);
  }

  // 4) attention
  attn_gpart<<<dim3(8, HH, BB), 256, 0, stream>>>(qcls, Ycls, part);
  attn_gcomb<<<BB * HH, 64, 0, stream>>>(part, ctxg);
  attn_local<<<dim3(SS / QBL, HH, BB), 256, 0, stream>>>(Yloc, CTX);

  // 5) local output projection -> all 4096 rows of d_out (rows 0,2048 overwritten next)
  {
    dim3 g3(M / 128, EE / 128);
    gemm_bt<0><<<g3, 256, 0, stream>>>(CTX, Wout, out_b_loc, out, M, EE, EE);
  }

  // 6) cls output rows
  gemv2<<<512, 256, 0, stream>>>(ctxg, EE, out_w_cls, out_b_cls,
                                 out, (size_t)SS * EE, EE, EE);
}

// Round 4
// 160.695 us; speedup vs baseline: 2.8547x; 1.0716x over previous
//
#include <hip/hip_runtime.h>

// Problem constants: B=2, S=2048, E=1024, H=16, D=64, WIN=16
#define BB 2
#define SS 2048
#define EE 1024
#define HH 16
#define DD 64
#define NY 5120   // merged projection output cols: [Kcls|Vcls|Qloc|Kloc|Vloc]

typedef __attribute__((ext_vector_type(8))) short short8;
typedef __attribute__((ext_vector_type(4))) float f32x4;

__device__ __forceinline__ float bf2f(unsigned short u) {
  union { unsigned int i; float f; } v; v.i = ((unsigned int)u) << 16; return v.f;
}
__device__ __forceinline__ unsigned short f2bf(float f) {
  unsigned int u = __float_as_uint(f);
  u += 0x7fff + ((u >> 16) & 1);   // RNE
  return (unsigned short)(u >> 16);
}
__device__ __forceinline__ void gload_lds16(const void* g, void* l) {
  __builtin_amdgcn_global_load_lds(
      (const __attribute__((address_space(1))) void*)g,
      (__attribute__((address_space(3))) void*)l, 16, 0, 0);
}

// ---------------- fused f32 -> bf16 casts (4 segments, 1 launch) ----------------
// seg0: hs (4096 blk), seg1: w_cls rows 1024..3071 (2048), seg2: w_loc (3072), seg3: w_out_loc (1024)
__global__ void cast_all(const float* __restrict__ s0, unsigned short* __restrict__ d0,
                         const float* __restrict__ s1, unsigned short* __restrict__ d1,
                         const float* __restrict__ s2, unsigned short* __restrict__ d2,
                         const float* __restrict__ s3, unsigned short* __restrict__ d3) {
  int b = blockIdx.x;
  const float* s; unsigned short* d; int idx;
  if (b < 4096)      { s = s0; d = d0; idx = b; }
  else if (b < 6144) { s = s1; d = d1; idx = b - 4096; }
  else if (b < 9216) { s = s2; d = d2; idx = b - 6144; }
  else               { s = s3; d = d3; idx = b - 9216; }
  int i = (idx * 256 + threadIdx.x) * 4;
  float4 v = *reinterpret_cast<const float4*>(s + i);
  ushort4 o;
  o.x = f2bf(v.x); o.y = f2bf(v.y); o.z = f2bf(v.z); o.w = f2bf(v.w);
  *reinterpret_cast<ushort4*>(d + i) = o;
}

// ---------------- bf16 GEMM: C[M,N] = A[M,K] @ B[N,K]^T + bias ----------------
// 128x128 tile, 4 waves, BK=32, double-buffered LDS with next-tile prefetch (T3-min),
// XCD-aware block swizzle (T1).
template <int OUT_BF16, int SPLIT>
__global__ __launch_bounds__(256, 4)
void gemm_bt(const unsigned short* __restrict__ A,
             const unsigned short* __restrict__ B,
             const float* __restrict__ bias0,
             const float* __restrict__ bias1,
             void* __restrict__ C, int M, int N, int K) {
  __shared__ unsigned short As[2][128 * 32];
  __shared__ unsigned short Bs[2][128 * 32];
  const int tid = threadIdx.x;
  const int wid = tid >> 6;
  const int lane = tid & 63;

  // XCD swizzle: bijective when nwg % 8 == 0 (both our grids satisfy this)
  const int nx = gridDim.x;
  int bid = blockIdx.y * nx + blockIdx.x;
  const int nwg = nx * gridDim.y;
  if ((nwg & 7) == 0) { int c = nwg >> 3; bid = (bid & 7) * c + (bid >> 3); }
  const int tileM = (bid % nx) * 128;
  const int tileN = (bid / nx) * 128;

  const int wm = (wid >> 1) * 64;
  const int wn = (wid & 1) * 64;
  const int rl = lane & 15;
  const int kc = (lane >> 4) * 8;

  f32x4 acc[4][4] = {};

  const int srow = tid >> 2;
  const int scol = (tid & 3) * 8;
  const unsigned short* gA = A + (size_t)(tileM + srow) * K + scol;
  const unsigned short* gB = B + (size_t)(tileN + srow) * K + scol;
  char* lA = (char*)As + wid * 1024;   // wave-uniform base within buf 0
  char* lB = (char*)Bs + wid * 1024;

  auto STAGE = [&](int buf, int k0) {
    gload_lds16(gA + k0, lA + buf * 8192);
    gload_lds16(gA + (size_t)64 * K + k0, lA + buf * 8192 + 4096);
    gload_lds16(gB + k0, lB + buf * 8192);
    gload_lds16(gB + (size_t)64 * K + k0, lB + buf * 8192 + 4096);
  };
  auto COMPUTE = [&](int buf) {
    const unsigned short* as = As[buf];
    const unsigned short* bs = Bs[buf];
    short8 af[4], bfg[4];
#pragma unroll
    for (int mi = 0; mi < 4; ++mi)
      af[mi] = *reinterpret_cast<const short8*>(&as[(wm + mi * 16 + rl) * 32 + kc]);
#pragma unroll
    for (int ni = 0; ni < 4; ++ni)
      bfg[ni] = *reinterpret_cast<const short8*>(&bs[(wn + ni * 16 + rl) * 32 + kc]);
#pragma unroll
    for (int mi = 0; mi < 4; ++mi)
#pragma unroll
      for (int ni = 0; ni < 4; ++ni)
        acc[mi][ni] = __builtin_amdgcn_mfma_f32_16x16x32_bf16(
            af[mi], bfg[ni], acc[mi][ni], 0, 0, 0);
  };

  // prologue
  STAGE(0, 0);
  asm volatile("s_waitcnt vmcnt(0)" ::: "memory");
  __syncthreads();
  int cur = 0;
  for (int k0 = 32; k0 < K; k0 += 32) {
    STAGE(cur ^ 1, k0);        // issue next tile's loads (fly during compute)
    COMPUTE(cur);
    asm volatile("s_waitcnt vmcnt(0)" ::: "memory");
    __syncthreads();
    cur ^= 1;
  }
  COMPUTE(cur);

  // epilogue: C/D layout col=lane&15, row=(lane>>4)*4+reg
  const int crow0 = (lane >> 4) * 4;
  const int ccol = lane & 15;
#pragma unroll
  for (int mi = 0; mi < 4; ++mi)
#pragma unroll
    for (int ni = 0; ni < 4; ++ni) {
      int gc = tileN + wn + ni * 16 + ccol;
      float bv;
      if (SPLIT) bv = (gc < 2048) ? bias0[1024 + gc] : bias1[gc - 2048];
      else       bv = bias0[gc];
#pragma unroll
      for (int r = 0; r < 4; ++r) {
        int gr = tileM + wm + mi * 16 + crow0 + r;
        if (gr < M) {
          float v = acc[mi][ni][r] + bv;
          if (OUT_BF16)
            ((unsigned short*)C)[(size_t)gr * N + gc] = f2bf(v);
          else
            ((float*)C)[(size_t)gr * N + gc] = v;
        }
      }
    }
}

// ---------------- tiny f32 GEMV: Y[b][n] = X[b]·W[n] + bias[n], b in {0,1} ----------------
__global__ void gemv2(const float* __restrict__ X, size_t xstride,
                      const float* __restrict__ W, const float* __restrict__ bias,
                      float* __restrict__ Y, size_t ystride, int N, int K) {
  int gw = blockIdx.x * 4 + (threadIdx.x >> 6);
  int lane = threadIdx.x & 63;
  if (gw >= 2 * N) return;
  int b = gw / N, n = gw % N;
  const float* x = X + (size_t)b * xstride;
  const float* w = W + (size_t)n * K;
  float s = 0.0f;
  for (int k = lane; k < K; k += 64) s += x[k] * w[k];
  for (int off = 32; off; off >>= 1) s += __shfl_xor(s, off);
  if (lane == 0) Y[(size_t)b * ystride + n] = s + bias[n];
}

// ---------------- global (cls) attention, phase A: partial per key-chunk ----------------
// Y cols: K_cls at h*64, V_cls at 1024+h*64 (row stride NY)
__global__ __launch_bounds__(256)
void attn_gpart(const float* __restrict__ qcls,
                const unsigned short* __restrict__ Y,
                float* __restrict__ part) {
  int kc = blockIdx.x, h = blockIdx.y, b = blockIdx.z;
  int tid = threadIdx.x;
  __shared__ float qf[64];
  __shared__ float ps[256];
  __shared__ float red[8];
  __shared__ float pacc[4][64];
  if (tid < 64) qf[tid] = qcls[b * EE + h * DD + tid];
  __syncthreads();

  int s = kc * 256 + tid;
  const short8* k8 = (const short8*)(Y + (size_t)(b * SS + s) * NY + h * DD);
  float dot = 0.0f;
#pragma unroll
  for (int i = 0; i < 8; ++i) {
    short8 kv = k8[i];
#pragma unroll
    for (int e = 0; e < 8; ++e) dot += qf[i * 8 + e] * bf2f((unsigned short)kv[e]);
  }
  dot *= 0.125f;

  float mx = dot;
  for (int o = 32; o; o >>= 1) mx = fmaxf(mx, __shfl_xor(mx, o));
  if ((tid & 63) == 0) red[tid >> 6] = mx;
  __syncthreads();
  float M = fmaxf(fmaxf(red[0], red[1]), fmaxf(red[2], red[3]));

  float p = __expf(dot - M);
  ps[tid] = p;
  float l = p;
  for (int o = 32; o; o >>= 1) l += __shfl_xor(l, o);
  if ((tid & 63) == 0) red[4 + (tid >> 6)] = l;
  __syncthreads();
  float L = red[4] + red[5] + red[6] + red[7];

  int g = tid >> 6, d = tid & 63;
  float acc = 0.0f;
  for (int sl = g; sl < 256; sl += 4)
    acc += ps[sl] * bf2f(Y[(size_t)(b * SS + kc * 256 + sl) * NY + 1024 + h * DD + d]);
  pacc[g][d] = acc;
  __syncthreads();
  if (g == 0) {
    float a = pacc[0][d] + pacc[1][d] + pacc[2][d] + pacc[3][d];
    float* pp = part + ((size_t)(b * HH + h) * 8 + kc) * 66;
    if (d == 0) { pp[0] = M; pp[1] = L; }
    pp[2 + d] = a;
  }
}

// phase B: combine 8 chunks.
__global__ void attn_gcomb(const float* __restrict__ part, float* __restrict__ ctxg) {
  int bh = blockIdx.x, d = threadIdx.x;
  const float* pp = part + (size_t)bh * 8 * 66;
  float M = -1e30f;
#pragma unroll
  for (int i = 0; i < 8; ++i) M = fmaxf(M, pp[i * 66]);
  float Z = 0.0f, a = 0.0f;
#pragma unroll
  for (int i = 0; i < 8; ++i) {
    float w = __expf(pp[i * 66] - M);
    Z += w * pp[i * 66 + 1];
    a += w * pp[i * 66 + 2 + d];
  }
  int b = bh >> 4, h = bh & 15;
  ctxg[b * EE + h * DD + d] = a / Z;
}

// ---------------- local attention via MFMA ----------------
// Y cols: Q_loc at 2048+h*64, K_loc at 3072+h*64, V_loc at 4096+h*64 (row stride NY)
#define QBL 128
#define VT_PAD 168
#define P_PAD 72
__global__ __launch_bounds__(256, 2)
void attn_local(const unsigned short* __restrict__ Y,
                unsigned short* __restrict__ CTX) {       // [4096][1024] bf16
  const int c = blockIdx.x, h = blockIdx.y, b = blockIdx.z;
  const int s0 = c * QBL;
  const int tid = threadIdx.x, wid = tid >> 6, lane = tid & 63;
  const int rl = lane & 15, g = lane >> 4;

  __shared__ unsigned short Vt[64][VT_PAD];     // V^T of key window [s0-16, s0+143]
  __shared__ unsigned short Pl[4][32][P_PAD];   // per-wave P (q x key)

  // stage V^T: task = chunk(8) x keypair(80); pack 2 keys per b32 write
  for (int task = tid; task < 640; task += 256) {
    int kp = task % 80, ch = task / 80;
    int k0 = kp * 2;
    int kg0 = min(max(s0 - 16 + k0, 0), SS - 1);
    int kg1 = min(max(s0 - 16 + k0 + 1, 0), SS - 1);
    short8 a = *(const short8*)&Y[(size_t)(b * SS + kg0) * NY + 4096 + h * DD + ch * 8];
    short8 bv = *(const short8*)&Y[(size_t)(b * SS + kg1) * NY + 4096 + h * DD + ch * 8];
#pragma unroll
    for (int e = 0; e < 8; ++e) {
      unsigned int w = (unsigned int)(unsigned short)a[e] |
                       ((unsigned int)(unsigned short)bv[e] << 16);
      *(unsigned int*)&Vt[ch * 8 + e][k0] = w;
    }
  }
  __syncthreads();

  const int qb = s0 + wid * 32;
  const int kb = qb - 16;

  short8 ak[4][2];
#pragma unroll
  for (int kt = 0; kt < 4; ++kt) {
    int kg = min(max(kb + kt * 16 + rl, 0), SS - 1);
    const unsigned short* kr = &Y[(size_t)(b * SS + kg) * NY + 3072 + h * DD + g * 8];
#pragma unroll
    for (int ks = 0; ks < 2; ++ks) ak[kt][ks] = *(const short8*)(kr + ks * 32);
  }
  short8 bq[2][2];
#pragma unroll
  for (int cc = 0; cc < 2; ++cc) {
    const unsigned short* qr = &Y[(size_t)(b * SS + qb + cc * 16 + rl) * NY + 2048 + h * DD + g * 8];
#pragma unroll
    for (int ks = 0; ks < 2; ++ks) bq[cc][ks] = *(const short8*)(qr + ks * 32);
  }

  f32x4 accs[4][2] = {};
#pragma unroll
  for (int kt = 0; kt < 4; ++kt)
#pragma unroll
    for (int cc = 0; cc < 2; ++cc)
#pragma unroll
      for (int ks = 0; ks < 2; ++ks)
        accs[kt][cc] = __builtin_amdgcn_mfma_f32_16x16x32_bf16(
            ak[kt][ks], bq[cc][ks], accs[kt][cc], 0, 0, 0);

  float mrow[2] = {-3e38f, -3e38f};
#pragma unroll
  for (int kt = 0; kt < 4; ++kt)
#pragma unroll
    for (int cc = 0; cc < 2; ++cc)
#pragma unroll
      for (int r = 0; r < 4; ++r) {
        int kg = kb + kt * 16 + 4 * g + r;
        int qg = qb + cc * 16 + rl;
        bool valid = (kg >= qg - 16) && (kg <= qg + 16) && (kg >= 1) && (kg < SS);
        float v = valid ? accs[kt][cc][r] : -3e38f;
        accs[kt][cc][r] = v;
        mrow[cc] = fmaxf(mrow[cc], v);
      }
#pragma unroll
  for (int cc = 0; cc < 2; ++cc) {
    float m = mrow[cc];
    m = fmaxf(m, __shfl_xor(m, 16));
    m = fmaxf(m, __shfl_xor(m, 32));
    mrow[cc] = m;
  }

  float zrow[2] = {0.0f, 0.0f};
#pragma unroll
  for (int cc = 0; cc < 2; ++cc)
#pragma unroll
    for (int kt = 0; kt < 4; ++kt) {
      ushort4 pw;
#pragma unroll
      for (int r = 0; r < 4; ++r) {
        float p = __expf((accs[kt][cc][r] - mrow[cc]) * 0.125f);
        zrow[cc] += p;
        ((unsigned short*)&pw)[r] = f2bf(p);
      }
      *(ushort4*)&Pl[wid][cc * 16 + rl][kt * 16 + 4 * g] = pw;
    }
#pragma unroll
  for (int cc = 0; cc < 2; ++cc) {
    float z = zrow[cc];
    z += __shfl_xor(z, 16);
    z += __shfl_xor(z, 32);
    zrow[cc] = 1.0f / z;
  }

  f32x4 accp[4][2] = {};
#pragma unroll
  for (int ks = 0; ks < 2; ++ks) {
    short8 bp[2];
#pragma unroll
    for (int cc = 0; cc < 2; ++cc)
      bp[cc] = *(const short8*)&Pl[wid][cc * 16 + rl][ks * 32 + g * 8];
#pragma unroll
    for (int mt = 0; mt < 4; ++mt) {
      short8 av = *(const short8*)&Vt[mt * 16 + rl][wid * 32 + ks * 32 + g * 8];
#pragma unroll
      for (int cc = 0; cc < 2; ++cc)
        accp[mt][cc] = __builtin_amdgcn_mfma_f32_16x16x32_bf16(
            av, bp[cc], accp[mt][cc], 0, 0, 0);
    }
  }

#pragma unroll
  for (int mt = 0; mt < 4; ++mt)
#pragma unroll
    for (int cc = 0; cc < 2; ++cc) {
      int token = qb + cc * 16 + rl;
      if (token == 0) {
        // reference leaves row 0 to the cls path; zero ctx so out-proj row 0 is benign
        *(ushort4*)&CTX[(size_t)(b * SS) * EE + h * DD + mt * 16 + 4 * g] = ushort4{0, 0, 0, 0};
        continue;
      }
      ushort4 o;
#pragma unroll
      for (int r = 0; r < 4; ++r)
        ((unsigned short*)&o)[r] = f2bf(accp[mt][cc][r] * zrow[cc]);
      *(ushort4*)&CTX[(size_t)(b * SS + token) * EE + h * DD + mt * 16 + 4 * g] = o;
    }
}

extern "C" void kernel_launch(void* const* d_in, const int* in_sizes, int n_in,
                              void* d_out, int out_size, void* d_ws, size_t ws_size,
                              hipStream_t stream) {
  const float* hs        = (const float*)d_in[0];
  const float* in_w_cls  = (const float*)d_in[1];
  const float* in_b_cls  = (const float*)d_in[2];
  const float* out_w_cls = (const float*)d_in[3];
  const float* out_b_cls = (const float*)d_in[4];
  const float* in_w_loc  = (const float*)d_in[5];
  const float* in_b_loc  = (const float*)d_in[6];
  const float* out_w_loc = (const float*)d_in[7];
  const float* out_b_loc = (const float*)d_in[8];
  float* out = (float*)d_out;

  const int M = BB * SS;  // 4096
  char* ws = (char*)d_ws;
  size_t off = 0;
  auto alloc = [&](size_t bytes) { char* p = ws + off; off += (bytes + 255) & ~(size_t)255; return p; };
  unsigned short* Xbf  = (unsigned short*)alloc((size_t)M * EE * 2);        // hs bf16
  unsigned short* W    = (unsigned short*)alloc((size_t)NY * EE * 2);       // merged weights [5120][1024]
  unsigned short* Wout = (unsigned short*)alloc((size_t)EE * EE * 2);       // out_w_loc
  unsigned short* Yb   = (unsigned short*)alloc((size_t)M * NY * 2);        // merged projections
  unsigned short* CTX  = (unsigned short*)alloc((size_t)M * EE * 2);        // local ctx
  float* qcls = (float*)alloc(2 * EE * 4);
  float* ctxg = (float*)alloc(2 * EE * 4);
  float* part = (float*)alloc((size_t)BB * HH * 8 * 66 * 4);

  // 1) fused casts (hs, cls k/v weights, loc weights, out_loc weights)
  cast_all<<<10240, 256, 0, stream>>>(
      hs, Xbf,
      in_w_cls + (size_t)EE * EE, W,
      in_w_loc, W + (size_t)2048 * EE,
      out_w_loc, Wout);

  // 2) q_cls (2 rows, f32)
  gemv2<<<512, 256, 0, stream>>>(hs, (size_t)SS * EE, in_w_cls, in_b_cls,
                                 qcls, EE, EE, EE);

  // 3) merged projection GEMM: Y = Xbf @ W^T + bias  (grid 32x40 = 1280 blocks)
  {
    dim3 g1(M / 128, NY / 128);
    gemm_bt<1, 1><<<g1, 256, 0, stream>>>(Xbf, W, in_b_cls, in_b_loc, Yb, M, NY, EE);
  }

  // 4) attention
  attn_gpart<<<dim3(8, HH, BB), 256, 0, stream>>>(qcls, Yb, part);
  attn_gcomb<<<BB * HH, 64, 0, stream>>>(part, ctxg);
  attn_local<<<dim3(SS / QBL, HH, BB), 256, 0, stream>>>(Yb, CTX);

  // 5) local output projection -> all 4096 rows of d_out (rows 0,2048 overwritten next)
  {
    dim3 g3(M / 128, EE / 128);
    gemm_bt<0, 0><<<g3, 256, 0, stream>>>(CTX, Wout, out_b_loc, nullptr, out, M, EE, EE);
  }

  // 6) cls output rows
  gemv2<<<512, 256, 0, stream>>>(ctxg, EE, out_w_cls, out_b_cls,
                                 out, (size_t)SS * EE, EE, EE);
}

// Round 5
// 145.657 us; speedup vs baseline: 3.1495x; 1.1032x over previous
//
#include <hip/hip_runtime.h>

// Problem constants: B=2, S=2048, E=1024, H=16, D=64, WIN=16
#define BB 2
#define SS 2048
#define EE 1024
#define HH 16
#define DD 64
#define NY 5120   // merged projection output cols: [Kcls|Vcls|Qloc|Kloc|Vloc]

typedef __attribute__((ext_vector_type(8))) short short8;
typedef __attribute__((ext_vector_type(4))) float f32x4;

__device__ __forceinline__ float bf2f(unsigned short u) {
  union { unsigned int i; float f; } v; v.i = ((unsigned int)u) << 16; return v.f;
}
__device__ __forceinline__ unsigned short f2bf(float f) {
  unsigned int u = __float_as_uint(f);
  u += 0x7fff + ((u >> 16) & 1);   // RNE
  return (unsigned short)(u >> 16);
}
__device__ __forceinline__ void gload_lds16(const void* g, void* l) {
  __builtin_amdgcn_global_load_lds(
      (const __attribute__((address_space(1))) void*)g,
      (__attribute__((address_space(3))) void*)l, 16, 0, 0);
}
__device__ __forceinline__ void gload_lds4(const void* g, void* l) {
  __builtin_amdgcn_global_load_lds(
      (const __attribute__((address_space(1))) void*)g,
      (__attribute__((address_space(3))) void*)l, 4, 0, 0);
}

// ---------------- fused f32 -> bf16 casts ----------------
__global__ void cast_all(const float* __restrict__ s0, unsigned short* __restrict__ d0,
                         const float* __restrict__ s1, unsigned short* __restrict__ d1,
                         const float* __restrict__ s2, unsigned short* __restrict__ d2,
                         const float* __restrict__ s3, unsigned short* __restrict__ d3) {
  int b = blockIdx.x;
  const float* s; unsigned short* d; int idx;
  if (b < 4096)      { s = s0; d = d0; idx = b; }
  else if (b < 6144) { s = s1; d = d1; idx = b - 4096; }
  else if (b < 9216) { s = s2; d = d2; idx = b - 6144; }
  else               { s = s3; d = d3; idx = b - 9216; }
  int i = (idx * 256 + threadIdx.x) * 4;
  float4 v = *reinterpret_cast<const float4*>(s + i);
  ushort4 o;
  o.x = f2bf(v.x); o.y = f2bf(v.y); o.z = f2bf(v.z); o.w = f2bf(v.w);
  *reinterpret_cast<ushort4*>(d + i) = o;
}

// ================= 8-phase 256x160 projection GEMM =================
// Y[4096][5120] = Xbf[4096][1024] @ W[5120][1024]^T + bias (bf16 out, f32 acc)
// 512 thr = 8 waves (4M x 2N), per-wave 64x80, BK=64, K=1024 (16 K-tiles, 8 iters).
// LDS: A 2x[256][64], B 2x[160][64] bf16, XOR-swizzled (byte bits 4-6 ^= (row&7)<<4).
// Staging per iteration: t+1.A(ph0,1) t+2.B(ph2,3) t+2.A(ph4,5) t+3.B(ph6,7);
// counted vmcnt(4) at phases 4 and 8 (slot-death-safe; see analysis in session log).
#define SBAR __builtin_amdgcn_sched_barrier(0)
#define RAWBAR do { SBAR; __builtin_amdgcn_s_barrier(); SBAR; } while (0)
#define WAITVM(n) do { asm volatile("s_waitcnt vmcnt(" #n ")" ::: "memory"); SBAR; } while (0)

#define MFMAP(p, a0, a1)                                                              \
  _Pragma("unroll")                                                                   \
  for (int ni = 0; ni < 5; ++ni) {                                                    \
    acc[p][ni] = __builtin_amdgcn_mfma_f32_16x16x32_bf16(a0, bf[ni][0], acc[p][ni], 0, 0, 0); \
    acc[p][ni] = __builtin_amdgcn_mfma_f32_16x16x32_bf16(a1, bf[ni][1], acc[p][ni], 0, 0, 0); \
  }

#define PHASE(c, p, STG, VM)                                        \
  {                                                                 \
    if ((p) == 0) DSB(c);                                           \
    short8 a2_0, a2_1;                                              \
    DSA(c, p, a2_0, a2_1);                                          \
    STG;                                                            \
    RAWBAR;                                                         \
    asm volatile("s_waitcnt lgkmcnt(0)" ::: "memory"); SBAR;        \
    __builtin_amdgcn_s_setprio(1);                                  \
    MFMAP(p, a2_0, a2_1);                                           \
    __builtin_amdgcn_s_setprio(0);                                  \
    VM;                                                             \
    RAWBAR;                                                         \
  }

__global__ __launch_bounds__(512, 2)
void gemm8p(const unsigned short* __restrict__ Ag,   // [4096][1024]
            const unsigned short* __restrict__ Bg,   // [5120][1024]
            const float* __restrict__ bcls,          // [3072]
            const float* __restrict__ bloc,          // [3072]
            unsigned short* __restrict__ Yout) {     // [4096][5120]
  __shared__ unsigned short As2[2][256][64];   // 64 KiB
  __shared__ unsigned short Bs2[2][160][64];   // 40 KiB
  char* ldsA = (char*)As2;
  char* ldsB = (char*)Bs2;

  const int tid = threadIdx.x;
  const int wid = tid >> 6;
  const int lane = tid & 63;
  const int wm = wid >> 1;        // 0..3 (64-row slice)
  const int wn = wid & 1;         // 0..1 (80-col slice)
  const int rl = lane & 15;
  const int g4 = lane >> 4;

  // XCD swizzle (512 % 8 == 0 -> simple bijective)
  int bid = blockIdx.y * 16 + blockIdx.x;
  bid = (bid & 7) * 64 + (bid >> 3);
  const int tileM = (bid & 15) * 256;
  const int tileN = (bid >> 4) * 160;

  f32x4 acc[4][5] = {};
  short8 bf[5][2];

  // ---- staging helpers: linear LDS dest, inverse-swizzled global source ----
  auto SA = [&](int c, int kk, int iss) {   // A: 4 x 16B issues per K-tile
    int flat = iss * 8192 + tid * 16;
    int row = flat >> 7;                              // 0..255
    int colb = (flat & 127) ^ ((row & 7) << 4);
    gload_lds16(Ag + (size_t)(tileM + row) * 1024 + kk + (colb >> 1),
                ldsA + c * 32768 + iss * 8192 + wid * 1024);
  };
  auto SB16 = [&](int c, int kk, int iss) { // B rows 0..127: 2 x 16B issues
    int flat = iss * 8192 + tid * 16;
    int row = flat >> 7;                              // 0..127
    int colb = (flat & 127) ^ ((row & 7) << 4);
    gload_lds16(Bg + (size_t)(tileN + row) * 1024 + kk + (colb >> 1),
                ldsB + c * 20480 + iss * 8192 + wid * 1024);
  };
  auto SB4 = [&](int c, int kk, int iss) {  // B rows 128..159: 2 x 4B issues
    int flat = 16384 + iss * 2048 + tid * 4;
    int row = flat >> 7;                              // 128..159
    int colb = (flat & 127) ^ ((row & 7) << 4);
    gload_lds4(Bg + (size_t)(tileN + row) * 1024 + kk + (colb >> 1),
               ldsB + c * 20480 + 16384 + iss * 2048 + wid * 256);
  };
  // ---- swizzled ds_reads ----
  auto DSA = [&](int c, int p, short8& a0, short8& a1) {
    int row = wm * 64 + p * 16 + rl;
    const char* base = ldsA + c * 32768 + row * 128;
    int sw = (row & 7) << 4;
    a0 = *(const short8*)(base + ((g4 * 16) ^ sw));
    a1 = *(const short8*)(base + ((64 + g4 * 16) ^ sw));
  };
  auto DSB = [&](int c) {
#pragma unroll
    for (int ni = 0; ni < 5; ++ni) {
      int row = wn * 80 + ni * 16 + rl;
      const char* base = ldsB + c * 20480 + row * 128;
      int sw = (row & 7) << 4;
      bf[ni][0] = *(const short8*)(base + ((g4 * 16) ^ sw));
      bf[ni][1] = *(const short8*)(base + ((64 + g4 * 16) ^ sw));
    }
  };

  // ---- prologue: tile0 (A+B) -> buf0, tile1.B -> buf1 ----
  SA(0, 0, 0); SA(0, 0, 1); SA(0, 0, 2); SA(0, 0, 3);
  SB16(0, 0, 0); SB16(0, 0, 1); SB4(0, 0, 0); SB4(0, 0, 1);
  SB16(1, 64, 0); SB16(1, 64, 1); SB4(1, 64, 0); SB4(1, 64, 1);
  WAITVM(4);            // tile0 landed; tile1.B (4 newest) still in flight
  RAWBAR;

  // ---- main loop: iterations 0..6 compute tiles (2i, 2i+1) ----
  for (int i = 0; i < 7; ++i) {
    const int kA1 = (2 * i + 1) * 64;
    const int k2  = (2 * i + 2) * 64;
    const int kB3 = (2 * i + 3) * 64;
    PHASE(0, 0, { SA(1, kA1, 0); SA(1, kA1, 1); }, );
    PHASE(0, 1, { SA(1, kA1, 2); SA(1, kA1, 3); }, );
    PHASE(0, 2, { SB16(0, k2, 0); SB16(0, k2, 1); }, );
    PHASE(0, 3, { SB4(0, k2, 0); SB4(0, k2, 1); }, WAITVM(4));
    PHASE(1, 0, { SA(0, k2, 0); SA(0, k2, 1); }, );
    PHASE(1, 1, { SA(0, k2, 2); SA(0, k2, 3); }, );
    PHASE(1, 2, { SB16(1, kB3, 0); SB16(1, kB3, 1); }, );
    PHASE(1, 3, { SB4(1, kB3, 0); SB4(1, kB3, 1); }, WAITVM(4));
  }
  // ---- peeled last iteration: tiles 14, 15 (no staging beyond tile15.A) ----
  {
    const int kA1 = 15 * 64;
    PHASE(0, 0, { SA(1, kA1, 0); SA(1, kA1, 1); }, );
    PHASE(0, 1, { SA(1, kA1, 2); SA(1, kA1, 3); }, );
    PHASE(0, 2, { }, );
    PHASE(0, 3, { }, WAITVM(0));
    PHASE(1, 0, { }, );
    PHASE(1, 1, { }, );
    PHASE(1, 2, { }, );
    PHASE(1, 3, { }, );
  }

  // ---- epilogue: C row = wm*64 + p*16 + g4*4 + r, col = wn*80 + ni*16 + rl ----
#pragma unroll
  for (int p = 0; p < 4; ++p)
#pragma unroll
    for (int ni = 0; ni < 5; ++ni) {
      int gc = tileN + wn * 80 + ni * 16 + rl;
      float bv = (gc < 2048) ? bcls[1024 + gc] : bloc[gc - 2048];
#pragma unroll
      for (int r = 0; r < 4; ++r) {
        int gr = tileM + wm * 64 + p * 16 + g4 * 4 + r;
        Yout[(size_t)gr * NY + gc] = f2bf(acc[p][ni][r] + bv);
      }
    }
}

// ---------------- 128x128 2-phase GEMM (out-proj only) ----------------
template <int OUT_BF16>
__global__ __launch_bounds__(256, 4)
void gemm_bt(const unsigned short* __restrict__ A,
             const unsigned short* __restrict__ B,
             const float* __restrict__ bias0,
             void* __restrict__ C, int M, int N, int K) {
  __shared__ unsigned short As[2][128 * 32];
  __shared__ unsigned short Bs[2][128 * 32];
  const int tid = threadIdx.x;
  const int wid = tid >> 6;
  const int lane = tid & 63;

  const int nx = gridDim.x;
  int bid = blockIdx.y * nx + blockIdx.x;
  const int nwg = nx * gridDim.y;
  if ((nwg & 7) == 0) { int c = nwg >> 3; bid = (bid & 7) * c + (bid >> 3); }
  const int tileM = (bid % nx) * 128;
  const int tileN = (bid / nx) * 128;

  const int wm = (wid >> 1) * 64;
  const int wn = (wid & 1) * 64;
  const int rl = lane & 15;
  const int kc = (lane >> 4) * 8;

  f32x4 acc[4][4] = {};

  const int srow = tid >> 2;
  const int scol = (tid & 3) * 8;
  const unsigned short* gA = A + (size_t)(tileM + srow) * K + scol;
  const unsigned short* gB = B + (size_t)(tileN + srow) * K + scol;
  char* lA = (char*)As + wid * 1024;
  char* lB = (char*)Bs + wid * 1024;

  auto STAGE = [&](int buf, int k0) {
    gload_lds16(gA + k0, lA + buf * 8192);
    gload_lds16(gA + (size_t)64 * K + k0, lA + buf * 8192 + 4096);
    gload_lds16(gB + k0, lB + buf * 8192);
    gload_lds16(gB + (size_t)64 * K + k0, lB + buf * 8192 + 4096);
  };
  auto COMPUTE = [&](int buf) {
    const unsigned short* as = As[buf];
    const unsigned short* bs = Bs[buf];
    short8 af[4], bfg[4];
#pragma unroll
    for (int mi = 0; mi < 4; ++mi)
      af[mi] = *reinterpret_cast<const short8*>(&as[(wm + mi * 16 + rl) * 32 + kc]);
#pragma unroll
    for (int ni = 0; ni < 4; ++ni)
      bfg[ni] = *reinterpret_cast<const short8*>(&bs[(wn + ni * 16 + rl) * 32 + kc]);
#pragma unroll
    for (int mi = 0; mi < 4; ++mi)
#pragma unroll
      for (int ni = 0; ni < 4; ++ni)
        acc[mi][ni] = __builtin_amdgcn_mfma_f32_16x16x32_bf16(
            af[mi], bfg[ni], acc[mi][ni], 0, 0, 0);
  };

  STAGE(0, 0);
  asm volatile("s_waitcnt vmcnt(0)" ::: "memory");
  __syncthreads();
  int cur = 0;
  for (int k0 = 32; k0 < K; k0 += 32) {
    STAGE(cur ^ 1, k0);
    COMPUTE(cur);
    asm volatile("s_waitcnt vmcnt(0)" ::: "memory");
    __syncthreads();
    cur ^= 1;
  }
  COMPUTE(cur);

  const int crow0 = (lane >> 4) * 4;
  const int ccol = lane & 15;
#pragma unroll
  for (int mi = 0; mi < 4; ++mi)
#pragma unroll
    for (int ni = 0; ni < 4; ++ni) {
      int gc = tileN + wn + ni * 16 + ccol;
      float bv = bias0[gc];
#pragma unroll
      for (int r = 0; r < 4; ++r) {
        int gr = tileM + wm + mi * 16 + crow0 + r;
        if (gr < M) {
          float v = acc[mi][ni][r] + bv;
          if (OUT_BF16)
            ((unsigned short*)C)[(size_t)gr * N + gc] = f2bf(v);
          else
            ((float*)C)[(size_t)gr * N + gc] = v;
        }
      }
    }
}

// ---------------- tiny f32 GEMV ----------------
__global__ void gemv2(const float* __restrict__ X, size_t xstride,
                      const float* __restrict__ W, const float* __restrict__ bias,
                      float* __restrict__ Y, size_t ystride, int N, int K) {
  int gw = blockIdx.x * 4 + (threadIdx.x >> 6);
  int lane = threadIdx.x & 63;
  if (gw >= 2 * N) return;
  int b = gw / N, n = gw % N;
  const float* x = X + (size_t)b * xstride;
  const float* w = W + (size_t)n * K;
  float s = 0.0f;
  for (int k = lane; k < K; k += 64) s += x[k] * w[k];
  for (int off = 32; off; off >>= 1) s += __shfl_xor(s, off);
  if (lane == 0) Y[(size_t)b * ystride + n] = s + bias[n];
}

// ---------------- global (cls) attention, phase A ----------------
__global__ __launch_bounds__(256)
void attn_gpart(const float* __restrict__ qcls,
                const unsigned short* __restrict__ Y,
                float* __restrict__ part) {
  int kc = blockIdx.x, h = blockIdx.y, b = blockIdx.z;
  int tid = threadIdx.x;
  __shared__ float qf[64];
  __shared__ float ps[256];
  __shared__ float red[8];
  __shared__ float pacc[4][64];
  if (tid < 64) qf[tid] = qcls[b * EE + h * DD + tid];
  __syncthreads();

  int s = kc * 256 + tid;
  const short8* k8 = (const short8*)(Y + (size_t)(b * SS + s) * NY + h * DD);
  float dot = 0.0f;
#pragma unroll
  for (int i = 0; i < 8; ++i) {
    short8 kv = k8[i];
#pragma unroll
    for (int e = 0; e < 8; ++e) dot += qf[i * 8 + e] * bf2f((unsigned short)kv[e]);
  }
  dot *= 0.125f;

  float mx = dot;
  for (int o = 32; o; o >>= 1) mx = fmaxf(mx, __shfl_xor(mx, o));
  if ((tid & 63) == 0) red[tid >> 6] = mx;
  __syncthreads();
  float M = fmaxf(fmaxf(red[0], red[1]), fmaxf(red[2], red[3]));

  float p = __expf(dot - M);
  ps[tid] = p;
  float l = p;
  for (int o = 32; o; o >>= 1) l += __shfl_xor(l, o);
  if ((tid & 63) == 0) red[4 + (tid >> 6)] = l;
  __syncthreads();
  float L = red[4] + red[5] + red[6] + red[7];

  int g = tid >> 6, d = tid & 63;
  float acc = 0.0f;
  for (int sl = g; sl < 256; sl += 4)
    acc += ps[sl] * bf2f(Y[(size_t)(b * SS + kc * 256 + sl) * NY + 1024 + h * DD + d]);
  pacc[g][d] = acc;
  __syncthreads();
  if (g == 0) {
    float a = pacc[0][d] + pacc[1][d] + pacc[2][d] + pacc[3][d];
    float* pp = part + ((size_t)(b * HH + h) * 8 + kc) * 66;
    if (d == 0) { pp[0] = M; pp[1] = L; }
    pp[2 + d] = a;
  }
}

__global__ void attn_gcomb(const float* __restrict__ part, float* __restrict__ ctxg) {
  int bh = blockIdx.x, d = threadIdx.x;
  const float* pp = part + (size_t)bh * 8 * 66;
  float M = -1e30f;
#pragma unroll
  for (int i = 0; i < 8; ++i) M = fmaxf(M, pp[i * 66]);
  float Z = 0.0f, a = 0.0f;
#pragma unroll
  for (int i = 0; i < 8; ++i) {
    float w = __expf(pp[i * 66] - M);
    Z += w * pp[i * 66 + 1];
    a += w * pp[i * 66 + 2 + d];
  }
  int b = bh >> 4, h = bh & 15;
  ctxg[b * EE + h * DD + d] = a / Z;
}

// ---------------- local attention via MFMA ----------------
#define QBL 128
#define VT_PAD 168
#define P_PAD 72
__global__ __launch_bounds__(256, 2)
void attn_local(const unsigned short* __restrict__ Y,
                unsigned short* __restrict__ CTX) {
  const int c = blockIdx.x, h = blockIdx.y, b = blockIdx.z;
  const int s0 = c * QBL;
  const int tid = threadIdx.x, wid = tid >> 6, lane = tid & 63;
  const int rl = lane & 15, g = lane >> 4;

  __shared__ unsigned short Vt[64][VT_PAD];
  __shared__ unsigned short Pl[4][32][P_PAD];

  for (int task = tid; task < 640; task += 256) {
    int kp = task % 80, ch = task / 80;
    int k0 = kp * 2;
    int kg0 = min(max(s0 - 16 + k0, 0), SS - 1);
    int kg1 = min(max(s0 - 16 + k0 + 1, 0), SS - 1);
    short8 a = *(const short8*)&Y[(size_t)(b * SS + kg0) * NY + 4096 + h * DD + ch * 8];
    short8 bv = *(const short8*)&Y[(size_t)(b * SS + kg1) * NY + 4096 + h * DD + ch * 8];
#pragma unroll
    for (int e = 0; e < 8; ++e) {
      unsigned int w = (unsigned int)(unsigned short)a[e] |
                       ((unsigned int)(unsigned short)bv[e] << 16);
      *(unsigned int*)&Vt[ch * 8 + e][k0] = w;
    }
  }
  __syncthreads();

  const int qb = s0 + wid * 32;
  const int kb = qb - 16;

  short8 ak[4][2];
#pragma unroll
  for (int kt = 0; kt < 4; ++kt) {
    int kg = min(max(kb + kt * 16 + rl, 0), SS - 1);
    const unsigned short* kr = &Y[(size_t)(b * SS + kg) * NY + 3072 + h * DD + g * 8];
#pragma unroll
    for (int ks = 0; ks < 2; ++ks) ak[kt][ks] = *(const short8*)(kr + ks * 32);
  }
  short8 bq[2][2];
#pragma unroll
  for (int cc = 0; cc < 2; ++cc) {
    const unsigned short* qr = &Y[(size_t)(b * SS + qb + cc * 16 + rl) * NY + 2048 + h * DD + g * 8];
#pragma unroll
    for (int ks = 0; ks < 2; ++ks) bq[cc][ks] = *(const short8*)(qr + ks * 32);
  }

  f32x4 accs[4][2] = {};
#pragma unroll
  for (int kt = 0; kt < 4; ++kt)
#pragma unroll
    for (int cc = 0; cc < 2; ++cc)
#pragma unroll
      for (int ks = 0; ks < 2; ++ks)
        accs[kt][cc] = __builtin_amdgcn_mfma_f32_16x16x32_bf16(
            ak[kt][ks], bq[cc][ks], accs[kt][cc], 0, 0, 0);

  float mrow[2] = {-3e38f, -3e38f};
#pragma unroll
  for (int kt = 0; kt < 4; ++kt)
#pragma unroll
    for (int cc = 0; cc < 2; ++cc)
#pragma unroll
      for (int r = 0; r < 4; ++r) {
        int kg = kb + kt * 16 + 4 * g + r;
        int qg = qb + cc * 16 + rl;
        bool valid = (kg >= qg - 16) && (kg <= qg + 16) && (kg >= 1) && (kg < SS);
        float v = valid ? accs[kt][cc][r] : -3e38f;
        accs[kt][cc][r] = v;
        mrow[cc] = fmaxf(mrow[cc], v);
      }
#pragma unroll
  for (int cc = 0; cc < 2; ++cc) {
    float m = mrow[cc];
    m = fmaxf(m, __shfl_xor(m, 16));
    m = fmaxf(m, __shfl_xor(m, 32));
    mrow[cc] = m;
  }

  float zrow[2] = {0.0f, 0.0f};
#pragma unroll
  for (int cc = 0; cc < 2; ++cc)
#pragma unroll
    for (int kt = 0; kt < 4; ++kt) {
      ushort4 pw;
#pragma unroll
      for (int r = 0; r < 4; ++r) {
        float p = __expf((accs[kt][cc][r] - mrow[cc]) * 0.125f);
        zrow[cc] += p;
        ((unsigned short*)&pw)[r] = f2bf(p);
      }
      *(ushort4*)&Pl[wid][cc * 16 + rl][kt * 16 + 4 * g] = pw;
    }
#pragma unroll
  for (int cc = 0; cc < 2; ++cc) {
    float z = zrow[cc];
    z += __shfl_xor(z, 16);
    z += __shfl_xor(z, 32);
    zrow[cc] = 1.0f / z;
  }

  f32x4 accp[4][2] = {};
#pragma unroll
  for (int ks = 0; ks < 2; ++ks) {
    short8 bp[2];
#pragma unroll
    for (int cc = 0; cc < 2; ++cc)
      bp[cc] = *(const short8*)&Pl[wid][cc * 16 + rl][ks * 32 + g * 8];
#pragma unroll
    for (int mt = 0; mt < 4; ++mt) {
      short8 av = *(const short8*)&Vt[mt * 16 + rl][wid * 32 + ks * 32 + g * 8];
#pragma unroll
      for (int cc = 0; cc < 2; ++cc)
        accp[mt][cc] = __builtin_amdgcn_mfma_f32_16x16x32_bf16(
            av, bp[cc], accp[mt][cc], 0, 0, 0);
    }
  }

#pragma unroll
  for (int mt = 0; mt < 4; ++mt)
#pragma unroll
    for (int cc = 0; cc < 2; ++cc) {
      int token = qb + cc * 16 + rl;
      if (token == 0) {
        *(ushort4*)&CTX[(size_t)(b * SS) * EE + h * DD + mt * 16 + 4 * g] = ushort4{0, 0, 0, 0};
        continue;
      }
      ushort4 o;
#pragma unroll
      for (int r = 0; r < 4; ++r)
        ((unsigned short*)&o)[r] = f2bf(accp[mt][cc][r] * zrow[cc]);
      *(ushort4*)&CTX[(size_t)(b * SS + token) * EE + h * DD + mt * 16 + 4 * g] = o;
    }
}

extern "C" void kernel_launch(void* const* d_in, const int* in_sizes, int n_in,
                              void* d_out, int out_size, void* d_ws, size_t ws_size,
                              hipStream_t stream) {
  const float* hs        = (const float*)d_in[0];
  const float* in_w_cls  = (const float*)d_in[1];
  const float* in_b_cls  = (const float*)d_in[2];
  const float* out_w_cls = (const float*)d_in[3];
  const float* out_b_cls = (const float*)d_in[4];
  const float* in_w_loc  = (const float*)d_in[5];
  const float* in_b_loc  = (const float*)d_in[6];
  const float* out_w_loc = (const float*)d_in[7];
  const float* out_b_loc = (const float*)d_in[8];
  float* out = (float*)d_out;

  const int M = BB * SS;  // 4096
  char* ws = (char*)d_ws;
  size_t off = 0;
  auto alloc = [&](size_t bytes) { char* p = ws + off; off += (bytes + 255) & ~(size_t)255; return p; };
  unsigned short* Xbf  = (unsigned short*)alloc((size_t)M * EE * 2);
  unsigned short* W    = (unsigned short*)alloc((size_t)NY * EE * 2);
  unsigned short* Wout = (unsigned short*)alloc((size_t)EE * EE * 2);
  unsigned short* Yb   = (unsigned short*)alloc((size_t)M * NY * 2);
  unsigned short* CTX  = (unsigned short*)alloc((size_t)M * EE * 2);
  float* qcls = (float*)alloc(2 * EE * 4);
  float* ctxg = (float*)alloc(2 * EE * 4);
  float* part = (float*)alloc((size_t)BB * HH * 8 * 66 * 4);

  // 1) fused casts
  cast_all<<<10240, 256, 0, stream>>>(
      hs, Xbf,
      in_w_cls + (size_t)EE * EE, W,
      in_w_loc, W + (size_t)2048 * EE,
      out_w_loc, Wout);

  // 2) q_cls (2 rows, f32)
  gemv2<<<512, 256, 0, stream>>>(hs, (size_t)SS * EE, in_w_cls, in_b_cls,
                                 qcls, EE, EE, EE);

  // 3) merged projection GEMM (8-phase, 256x160 tiles, 512 blocks = 2/CU)
  gemm8p<<<dim3(16, 32), 512, 0, stream>>>(Xbf, W, in_b_cls, in_b_loc, Yb);

  // 4) attention
  attn_gpart<<<dim3(8, HH, BB), 256, 0, stream>>>(qcls, Yb, part);
  attn_gcomb<<<BB * HH, 64, 0, stream>>>(part, ctxg);
  attn_local<<<dim3(SS / QBL, HH, BB), 256, 0, stream>>>(Yb, CTX);

  // 5) local output projection
  {
    dim3 g3(M / 128, EE / 128);
    gemm_bt<0><<<g3, 256, 0, stream>>>(CTX, Wout, out_b_loc, out, M, EE, EE);
  }

  // 6) cls output rows
  gemv2<<<512, 256, 0, stream>>>(ctxg, EE, out_w_cls, out_b_cls,
                                 out, (size_t)SS * EE, EE, EE);
}

// Round 6
// 133.225 us; speedup vs baseline: 3.4434x; 1.0933x over previous
//
#include <hip/hip_runtime.h>

// Problem constants: B=2, S=2048, E=1024, H=16, D=64, WIN=16
#define BB 2
#define SS 2048
#define EE 1024
#define HH 16
#define DD 64
#define NY 5120   // merged projection output cols: [Kcls|Vcls|Qloc|Kloc|Vloc]

typedef __attribute__((ext_vector_type(8))) short short8;
typedef __attribute__((ext_vector_type(4))) float f32x4;

__device__ __forceinline__ float bf2f(unsigned short u) {
  union { unsigned int i; float f; } v; v.i = ((unsigned int)u) << 16; return v.f;
}
__device__ __forceinline__ unsigned short f2bf(float f) {
  unsigned int u = __float_as_uint(f);
  u += 0x7fff + ((u >> 16) & 1);   // RNE
  return (unsigned short)(u >> 16);
}
__device__ __forceinline__ void gload_lds16(const void* g, void* l) {
  __builtin_amdgcn_global_load_lds(
      (const __attribute__((address_space(1))) void*)g,
      (__attribute__((address_space(3))) void*)l, 16, 0, 0);
}

// ---------------- fused f32->bf16 casts + q_cls GEMV (one launch) ----------------
__global__ void cast_all(const float* __restrict__ s0, unsigned short* __restrict__ d0,
                         const float* __restrict__ s1, unsigned short* __restrict__ d1,
                         const float* __restrict__ s2, unsigned short* __restrict__ d2,
                         const float* __restrict__ s3, unsigned short* __restrict__ d3,
                         const float* __restrict__ in_w_cls,
                         const float* __restrict__ in_b_cls,
                         float* __restrict__ qcls) {
  int b = blockIdx.x;
  if (b >= 10240) {   // q_cls GEMV: 512 blocks x 4 rows
    int gw = (b - 10240) * 4 + (threadIdx.x >> 6);
    int lane = threadIdx.x & 63;
    int bb = gw >> 10, n = gw & 1023;
    const float* x = s0 + (size_t)bb * SS * EE;   // hs row of token 0
    const float* w = in_w_cls + (size_t)n * EE;
    float s = 0.0f;
    for (int k = lane; k < EE; k += 64) s += x[k] * w[k];
    for (int o = 32; o; o >>= 1) s += __shfl_xor(s, o);
    if (lane == 0) qcls[bb * EE + n] = s + in_b_cls[n];
    return;
  }
  const float* s; unsigned short* d; int idx;
  if (b < 4096)      { s = s0; d = d0; idx = b; }
  else if (b < 6144) { s = s1; d = d1; idx = b - 4096; }
  else if (b < 9216) { s = s2; d = d2; idx = b - 6144; }
  else               { s = s3; d = d3; idx = b - 9216; }
  int i = (idx * 256 + threadIdx.x) * 4;
  float4 v = *reinterpret_cast<const float4*>(s + i);
  ushort4 o;
  o.x = f2bf(v.x); o.y = f2bf(v.y); o.z = f2bf(v.z); o.w = f2bf(v.w);
  *reinterpret_cast<ushort4*>(d + i) = o;
}

// ================= 8-phase 256x320 projection GEMM =================
// Y[4096][5120] = Xbf[4096][1024] @ W[5120][1024]^T + bias
// 512 thr = 8 waves (2M x 4N), per-wave 128x80 (acc 8x5), BK=64, 16 K-tiles.
// Phases per K-tile = (m-half x k-half): 20 MFMA each; B frags persist per k-half.
// LDS 144 KiB: A 2x[256][64], B 2x[320][64], XOR swizzle byte^=(row&7)<<4.
// Staging: t+1 rolled during t (A:2+2, B:3+2 issues); vmcnt(0) only at tile seam
// (issues have >=1 full phase of latency cover). Grid 256 = 1 block/CU, 1 round.
#define SBAR __builtin_amdgcn_sched_barrier(0)
#define RAWBAR do { SBAR; __builtin_amdgcn_s_barrier(); SBAR; } while (0)
#define WAITVM0 do { asm volatile("s_waitcnt vmcnt(0)" ::: "memory"); SBAR; } while (0)
#define LGKM0 do { asm volatile("s_waitcnt lgkmcnt(0)" ::: "memory"); SBAR; } while (0)

#define MFMA20(MH)                                                                   \
  _Pragma("unroll")                                                                  \
  for (int m = 0; m < 4; ++m)                                                        \
    _Pragma("unroll")                                                                \
    for (int n = 0; n < 5; ++n)                                                      \
      acc[(MH) * 4 + m][n] = __builtin_amdgcn_mfma_f32_16x16x32_bf16(                \
          afr[m], bfr[n], acc[(MH) * 4 + m][n], 0, 0, 0);

__global__ __launch_bounds__(512, 2)
void gemm8p(const unsigned short* __restrict__ Ag,   // [4096][1024]
            const unsigned short* __restrict__ Bg,   // [5120][1024]
            const float* __restrict__ bcls,
            const float* __restrict__ bloc,
            unsigned short* __restrict__ Yout) {     // [4096][5120]
  __shared__ unsigned short As2[2][256][64];   // 64 KiB
  __shared__ unsigned short Bs2[2][320][64];   // 80 KiB
  char* ldsA = (char*)As2;
  char* ldsB = (char*)Bs2;

  const int tid = threadIdx.x;
  const int wid = tid >> 6;
  const int lane = tid & 63;
  const int wm = wid >> 2;     // 0..1 -> 128-row slice
  const int wn = wid & 3;      // 0..3 -> 80-col slice
  const int rl = lane & 15;
  const int g4 = lane >> 4;

  int bid = blockIdx.x;
  bid = (bid & 7) * 32 + (bid >> 3);     // XCD swizzle, bijective (256 = 8*32)
  const int tileM = (bid & 15) * 256;
  const int tileN = (bid >> 4) * 320;

  f32x4 acc[8][5] = {};
  short8 afr[4], bfr[5];

  auto SA = [&](int c, int kk, int i) {
    int flat = i * 8192 + tid * 16;
    int row = flat >> 7;
    int colb = (flat & 127) ^ ((row & 7) << 4);
    gload_lds16(Ag + (size_t)(tileM + row) * 1024 + kk + (colb >> 1),
                ldsA + c * 32768 + i * 8192 + wid * 1024);
  };
  auto SB = [&](int c, int kk, int j) {
    int flat = j * 8192 + tid * 16;
    int row = flat >> 7;
    int colb = (flat & 127) ^ ((row & 7) << 4);
    gload_lds16(Bg + (size_t)(tileN + row) * 1024 + kk + (colb >> 1),
                ldsB + c * 40960 + j * 8192 + wid * 1024);
  };
  auto DSA = [&](int c, int mh, int kh) {
#pragma unroll
    for (int m = 0; m < 4; ++m) {
      int row = wm * 128 + mh * 64 + m * 16 + rl;
      const char* base = ldsA + c * 32768 + row * 128;
      afr[m] = *(const short8*)(base + ((kh * 64 + g4 * 16) ^ ((row & 7) << 4)));
    }
  };
  auto DSB = [&](int c, int kh) {
#pragma unroll
    for (int n = 0; n < 5; ++n) {
      int row = wn * 80 + n * 16 + rl;
      const char* base = ldsB + c * 40960 + row * 128;
      bfr[n] = *(const short8*)(base + ((kh * 64 + g4 * 16) ^ ((row & 7) << 4)));
    }
  };

  // prologue: tile 0 -> buf0
  SA(0, 0, 0); SA(0, 0, 1); SA(0, 0, 2); SA(0, 0, 3);
  SB(0, 0, 0); SB(0, 0, 1); SB(0, 0, 2); SB(0, 0, 3); SB(0, 0, 4);
  WAITVM0;
  RAWBAR;

#pragma unroll 1
  for (int t = 0; t < 16; ++t) {
    const int c = t & 1;
    const int kk = (t + 1) * 64;
    const bool st = (t < 15);
    // phase 0: (m-half 0, k-half 0)
    DSB(c, 0); DSA(c, 0, 0);
    if (st) { SA(c ^ 1, kk, 0); SA(c ^ 1, kk, 1); }
    RAWBAR; LGKM0;
    __builtin_amdgcn_s_setprio(1); MFMA20(0); __builtin_amdgcn_s_setprio(0);
    RAWBAR;
    // phase 1: (m-half 1, k-half 0)
    DSA(c, 1, 0);
    if (st) { SA(c ^ 1, kk, 2); SA(c ^ 1, kk, 3); }
    RAWBAR; LGKM0;
    __builtin_amdgcn_s_setprio(1); MFMA20(1); __builtin_amdgcn_s_setprio(0);
    RAWBAR;
    // phase 2: (m-half 0, k-half 1)
    DSB(c, 1); DSA(c, 0, 1);
    if (st) { SB(c ^ 1, kk, 0); SB(c ^ 1, kk, 1); SB(c ^ 1, kk, 2); }
    RAWBAR; LGKM0;
    __builtin_amdgcn_s_setprio(1); MFMA20(0); __builtin_amdgcn_s_setprio(0);
    RAWBAR;
    // phase 3: (m-half 1, k-half 1)
    DSA(c, 1, 1);
    if (st) { SB(c ^ 1, kk, 3); SB(c ^ 1, kk, 4); }
    RAWBAR; LGKM0;
    __builtin_amdgcn_s_setprio(1); MFMA20(1); __builtin_amdgcn_s_setprio(0);
    if (st) WAITVM0;       // tile seam: t+1 fully landed (issues >=1 phase old)
    RAWBAR;
  }

  // epilogue: C row = tileM + wm*128 + m*16 + g4*4 + r, col = tileN + wn*80 + n*16 + rl
#pragma unroll
  for (int m = 0; m < 8; ++m)
#pragma unroll
    for (int n = 0; n < 5; ++n) {
      int gc = tileN + wn * 80 + n * 16 + rl;
      float bv = (gc < 2048) ? bcls[1024 + gc] : bloc[gc - 2048];
#pragma unroll
      for (int r = 0; r < 4; ++r) {
        int gr = tileM + wm * 128 + m * 16 + g4 * 4 + r;
        Yout[(size_t)gr * NY + gc] = f2bf(acc[m][n][r] + bv);
      }
    }
}

// ---------------- 128x128 2-phase GEMM (out-proj only) ----------------
template <int OUT_BF16>
__global__ __launch_bounds__(256, 4)
void gemm_bt(const unsigned short* __restrict__ A,
             const unsigned short* __restrict__ B,
             const float* __restrict__ bias0,
             void* __restrict__ C, int M, int N, int K) {
  __shared__ unsigned short As[2][128 * 32];
  __shared__ unsigned short Bs[2][128 * 32];
  const int tid = threadIdx.x;
  const int wid = tid >> 6;
  const int lane = tid & 63;

  const int nx = gridDim.x;
  int bid = blockIdx.y * nx + blockIdx.x;
  const int nwg = nx * gridDim.y;
  if ((nwg & 7) == 0) { int c = nwg >> 3; bid = (bid & 7) * c + (bid >> 3); }
  const int tileM = (bid % nx) * 128;
  const int tileN = (bid / nx) * 128;

  const int wm = (wid >> 1) * 64;
  const int wn = (wid & 1) * 64;
  const int rl = lane & 15;
  const int kc = (lane >> 4) * 8;

  f32x4 acc[4][4] = {};

  const int srow = tid >> 2;
  const int scol = (tid & 3) * 8;
  const unsigned short* gA = A + (size_t)(tileM + srow) * K + scol;
  const unsigned short* gB = B + (size_t)(tileN + srow) * K + scol;
  char* lA = (char*)As + wid * 1024;
  char* lB = (char*)Bs + wid * 1024;

  auto STAGE = [&](int buf, int k0) {
    gload_lds16(gA + k0, lA + buf * 8192);
    gload_lds16(gA + (size_t)64 * K + k0, lA + buf * 8192 + 4096);
    gload_lds16(gB + k0, lB + buf * 8192);
    gload_lds16(gB + (size_t)64 * K + k0, lB + buf * 8192 + 4096);
  };
  auto COMPUTE = [&](int buf) {
    const unsigned short* as = As[buf];
    const unsigned short* bs = Bs[buf];
    short8 af[4], bfg[4];
#pragma unroll
    for (int mi = 0; mi < 4; ++mi)
      af[mi] = *reinterpret_cast<const short8*>(&as[(wm + mi * 16 + rl) * 32 + kc]);
#pragma unroll
    for (int ni = 0; ni < 4; ++ni)
      bfg[ni] = *reinterpret_cast<const short8*>(&bs[(wn + ni * 16 + rl) * 32 + kc]);
#pragma unroll
    for (int mi = 0; mi < 4; ++mi)
#pragma unroll
      for (int ni = 0; ni < 4; ++ni)
        acc[mi][ni] = __builtin_amdgcn_mfma_f32_16x16x32_bf16(
            af[mi], bfg[ni], acc[mi][ni], 0, 0, 0);
  };

  STAGE(0, 0);
  asm volatile("s_waitcnt vmcnt(0)" ::: "memory");
  __syncthreads();
  int cur = 0;
  for (int k0 = 32; k0 < K; k0 += 32) {
    STAGE(cur ^ 1, k0);
    COMPUTE(cur);
    asm volatile("s_waitcnt vmcnt(0)" ::: "memory");
    __syncthreads();
    cur ^= 1;
  }
  COMPUTE(cur);

  const int crow0 = (lane >> 4) * 4;
  const int ccol = lane & 15;
#pragma unroll
  for (int mi = 0; mi < 4; ++mi)
#pragma unroll
    for (int ni = 0; ni < 4; ++ni) {
      int gc = tileN + wn + ni * 16 + ccol;
      float bv = bias0[gc];
#pragma unroll
      for (int r = 0; r < 4; ++r) {
        int gr = tileM + wm + mi * 16 + crow0 + r;
        if (gr < M) {
          float v = acc[mi][ni][r] + bv;
          if (OUT_BF16)
            ((unsigned short*)C)[(size_t)gr * N + gc] = f2bf(v);
          else
            ((float*)C)[(size_t)gr * N + gc] = v;
        }
      }
    }
}

// ---------------- tiny f32 GEMV (final cls rows) ----------------
__global__ void gemv2(const float* __restrict__ X, size_t xstride,
                      const float* __restrict__ W, const float* __restrict__ bias,
                      float* __restrict__ Y, size_t ystride, int N, int K) {
  int gw = blockIdx.x * 4 + (threadIdx.x >> 6);
  int lane = threadIdx.x & 63;
  if (gw >= 2 * N) return;
  int b = gw / N, n = gw % N;
  const float* x = X + (size_t)b * xstride;
  const float* w = W + (size_t)n * K;
  float s = 0.0f;
  for (int k = lane; k < K; k += 64) s += x[k] * w[k];
  for (int off = 32; off; off >>= 1) s += __shfl_xor(s, off);
  if (lane == 0) Y[(size_t)b * ystride + n] = s + bias[n];
}

// ---------------- global (cls) attention, phase A ----------------
__global__ __launch_bounds__(256)
void attn_gpart(const float* __restrict__ qcls,
                const unsigned short* __restrict__ Y,
                float* __restrict__ part) {
  int kc = blockIdx.x, h = blockIdx.y, b = blockIdx.z;
  int tid = threadIdx.x;
  __shared__ float qf[64];
  __shared__ float ps[256];
  __shared__ float red[8];
  __shared__ float pacc[4][64];
  if (tid < 64) qf[tid] = qcls[b * EE + h * DD + tid];
  __syncthreads();

  int s = kc * 256 + tid;
  const short8* k8 = (const short8*)(Y + (size_t)(b * SS + s) * NY + h * DD);
  float dot = 0.0f;
#pragma unroll
  for (int i = 0; i < 8; ++i) {
    short8 kv = k8[i];
#pragma unroll
    for (int e = 0; e < 8; ++e) dot += qf[i * 8 + e] * bf2f((unsigned short)kv[e]);
  }
  dot *= 0.125f;

  float mx = dot;
  for (int o = 32; o; o >>= 1) mx = fmaxf(mx, __shfl_xor(mx, o));
  if ((tid & 63) == 0) red[tid >> 6] = mx;
  __syncthreads();
  float M = fmaxf(fmaxf(red[0], red[1]), fmaxf(red[2], red[3]));

  float p = __expf(dot - M);
  ps[tid] = p;
  float l = p;
  for (int o = 32; o; o >>= 1) l += __shfl_xor(l, o);
  if ((tid & 63) == 0) red[4 + (tid >> 6)] = l;
  __syncthreads();
  float L = red[4] + red[5] + red[6] + red[7];

  int g = tid >> 6, d = tid & 63;
  float acc = 0.0f;
  for (int sl = g; sl < 256; sl += 4)
    acc += ps[sl] * bf2f(Y[(size_t)(b * SS + kc * 256 + sl) * NY + 1024 + h * DD + d]);
  pacc[g][d] = acc;
  __syncthreads();
  if (g == 0) {
    float a = pacc[0][d] + pacc[1][d] + pacc[2][d] + pacc[3][d];
    float* pp = part + ((size_t)(b * HH + h) * 8 + kc) * 66;
    if (d == 0) { pp[0] = M; pp[1] = L; }
    pp[2 + d] = a;
  }
}

__global__ void attn_gcomb(const float* __restrict__ part, float* __restrict__ ctxg) {
  int bh = blockIdx.x, d = threadIdx.x;
  const float* pp = part + (size_t)bh * 8 * 66;
  float M = -1e30f;
#pragma unroll
  for (int i = 0; i < 8; ++i) M = fmaxf(M, pp[i * 66]);
  float Z = 0.0f, a = 0.0f;
#pragma unroll
  for (int i = 0; i < 8; ++i) {
    float w = __expf(pp[i * 66] - M);
    Z += w * pp[i * 66 + 1];
    a += w * pp[i * 66 + 2 + d];
  }
  int b = bh >> 4, h = bh & 15;
  ctxg[b * EE + h * DD + d] = a / Z;
}

// ---------------- local attention via MFMA ----------------
#define QBL 128
#define VT_PAD 168
#define P_PAD 72
__global__ __launch_bounds__(256, 2)
void attn_local(const unsigned short* __restrict__ Y,
                unsigned short* __restrict__ CTX) {
  const int c = blockIdx.x, h = blockIdx.y, b = blockIdx.z;
  const int s0 = c * QBL;
  const int tid = threadIdx.x, wid = tid >> 6, lane = tid & 63;
  const int rl = lane & 15, g = lane >> 4;

  __shared__ unsigned short Vt[64][VT_PAD];
  __shared__ unsigned short Pl[4][32][P_PAD];

  for (int task = tid; task < 640; task += 256) {
    int kp = task % 80, ch = task / 80;
    int k0 = kp * 2;
    int kg0 = min(max(s0 - 16 + k0, 0), SS - 1);
    int kg1 = min(max(s0 - 16 + k0 + 1, 0), SS - 1);
    short8 a = *(const short8*)&Y[(size_t)(b * SS + kg0) * NY + 4096 + h * DD + ch * 8];
    short8 bv = *(const short8*)&Y[(size_t)(b * SS + kg1) * NY + 4096 + h * DD + ch * 8];
#pragma unroll
    for (int e = 0; e < 8; ++e) {
      unsigned int w = (unsigned int)(unsigned short)a[e] |
                       ((unsigned int)(unsigned short)bv[e] << 16);
      *(unsigned int*)&Vt[ch * 8 + e][k0] = w;
    }
  }
  __syncthreads();

  const int qb = s0 + wid * 32;
  const int kb = qb - 16;

  short8 ak[4][2];
#pragma unroll
  for (int kt = 0; kt < 4; ++kt) {
    int kg = min(max(kb + kt * 16 + rl, 0), SS - 1);
    const unsigned short* kr = &Y[(size_t)(b * SS + kg) * NY + 3072 + h * DD + g * 8];
#pragma unroll
    for (int ks = 0; ks < 2; ++ks) ak[kt][ks] = *(const short8*)(kr + ks * 32);
  }
  short8 bq[2][2];
#pragma unroll
  for (int cc = 0; cc < 2; ++cc) {
    const unsigned short* qr = &Y[(size_t)(b * SS + qb + cc * 16 + rl) * NY + 2048 + h * DD + g * 8];
#pragma unroll
    for (int ks = 0; ks < 2; ++ks) bq[cc][ks] = *(const short8*)(qr + ks * 32);
  }

  f32x4 accs[4][2] = {};
#pragma unroll
  for (int kt = 0; kt < 4; ++kt)
#pragma unroll
    for (int cc = 0; cc < 2; ++cc)
#pragma unroll
      for (int ks = 0; ks < 2; ++ks)
        accs[kt][cc] = __builtin_amdgcn_mfma_f32_16x16x32_bf16(
            ak[kt][ks], bq[cc][ks], accs[kt][cc], 0, 0, 0);

  float mrow[2] = {-3e38f, -3e38f};
#pragma unroll
  for (int kt = 0; kt < 4; ++kt)
#pragma unroll
    for (int cc = 0; cc < 2; ++cc)
#pragma unroll
      for (int r = 0; r < 4; ++r) {
        int kg = kb + kt * 16 + 4 * g + r;
        int qg = qb + cc * 16 + rl;
        bool valid = (kg >= qg - 16) && (kg <= qg + 16) && (kg >= 1) && (kg < SS);
        float v = valid ? accs[kt][cc][r] : -3e38f;
        accs[kt][cc][r] = v;
        mrow[cc] = fmaxf(mrow[cc], v);
      }
#pragma unroll
  for (int cc = 0; cc < 2; ++cc) {
    float m = mrow[cc];
    m = fmaxf(m, __shfl_xor(m, 16));
    m = fmaxf(m, __shfl_xor(m, 32));
    mrow[cc] = m;
  }

  float zrow[2] = {0.0f, 0.0f};
#pragma unroll
  for (int cc = 0; cc < 2; ++cc)
#pragma unroll
    for (int kt = 0; kt < 4; ++kt) {
      ushort4 pw;
#pragma unroll
      for (int r = 0; r < 4; ++r) {
        float p = __expf((accs[kt][cc][r] - mrow[cc]) * 0.125f);
        zrow[cc] += p;
        ((unsigned short*)&pw)[r] = f2bf(p);
      }
      *(ushort4*)&Pl[wid][cc * 16 + rl][kt * 16 + 4 * g] = pw;
    }
#pragma unroll
  for (int cc = 0; cc < 2; ++cc) {
    float z = zrow[cc];
    z += __shfl_xor(z, 16);
    z += __shfl_xor(z, 32);
    zrow[cc] = 1.0f / z;
  }

  f32x4 accp[4][2] = {};
#pragma unroll
  for (int ks = 0; ks < 2; ++ks) {
    short8 bp[2];
#pragma unroll
    for (int cc = 0; cc < 2; ++cc)
      bp[cc] = *(const short8*)&Pl[wid][cc * 16 + rl][ks * 32 + g * 8];
#pragma unroll
    for (int mt = 0; mt < 4; ++mt) {
      short8 av = *(const short8*)&Vt[mt * 16 + rl][wid * 32 + ks * 32 + g * 8];
#pragma unroll
      for (int cc = 0; cc < 2; ++cc)
        accp[mt][cc] = __builtin_amdgcn_mfma_f32_16x16x32_bf16(
            av, bp[cc], accp[mt][cc], 0, 0, 0);
    }
  }

#pragma unroll
  for (int mt = 0; mt < 4; ++mt)
#pragma unroll
    for (int cc = 0; cc < 2; ++cc) {
      int token = qb + cc * 16 + rl;
      if (token == 0) {
        *(ushort4*)&CTX[(size_t)(b * SS) * EE + h * DD + mt * 16 + 4 * g] = ushort4{0, 0, 0, 0};
        continue;
      }
      ushort4 o;
#pragma unroll
      for (int r = 0; r < 4; ++r)
        ((unsigned short*)&o)[r] = f2bf(accp[mt][cc][r] * zrow[cc]);
      *(ushort4*)&CTX[(size_t)(b * SS + token) * EE + h * DD + mt * 16 + 4 * g] = o;
    }
}

extern "C" void kernel_launch(void* const* d_in, const int* in_sizes, int n_in,
                              void* d_out, int out_size, void* d_ws, size_t ws_size,
                              hipStream_t stream) {
  const float* hs        = (const float*)d_in[0];
  const float* in_w_cls  = (const float*)d_in[1];
  const float* in_b_cls  = (const float*)d_in[2];
  const float* out_w_cls = (const float*)d_in[3];
  const float* out_b_cls = (const float*)d_in[4];
  const float* in_w_loc  = (const float*)d_in[5];
  const float* in_b_loc  = (const float*)d_in[6];
  const float* out_w_loc = (const float*)d_in[7];
  const float* out_b_loc = (const float*)d_in[8];
  float* out = (float*)d_out;

  const int M = BB * SS;  // 4096
  char* ws = (char*)d_ws;
  size_t off = 0;
  auto alloc = [&](size_t bytes) { char* p = ws + off; off += (bytes + 255) & ~(size_t)255; return p; };
  unsigned short* Xbf  = (unsigned short*)alloc((size_t)M * EE * 2);
  unsigned short* W    = (unsigned short*)alloc((size_t)NY * EE * 2);
  unsigned short* Wout = (unsigned short*)alloc((size_t)EE * EE * 2);
  unsigned short* Yb   = (unsigned short*)alloc((size_t)M * NY * 2);
  unsigned short* CTX  = (unsigned short*)alloc((size_t)M * EE * 2);
  float* qcls = (float*)alloc(2 * EE * 4);
  float* ctxg = (float*)alloc(2 * EE * 4);
  float* part = (float*)alloc((size_t)BB * HH * 8 * 66 * 4);

  // 1) fused casts + q_cls GEMV
  cast_all<<<10752, 256, 0, stream>>>(
      hs, Xbf,
      in_w_cls + (size_t)EE * EE, W,
      in_w_loc, W + (size_t)2048 * EE,
      out_w_loc, Wout,
      in_w_cls, in_b_cls, qcls);

  // 2) merged projection GEMM (8-phase, 256x320 tiles, 256 blocks = 1 round)
  gemm8p<<<256, 512, 0, stream>>>(Xbf, W, in_b_cls, in_b_loc, Yb);

  // 3) attention
  attn_gpart<<<dim3(8, HH, BB), 256, 0, stream>>>(qcls, Yb, part);
  attn_gcomb<<<BB * HH, 64, 0, stream>>>(part, ctxg);
  attn_local<<<dim3(SS / QBL, HH, BB), 256, 0, stream>>>(Yb, CTX);

  // 4) local output projection
  {
    dim3 g3(M / 128, EE / 128);
    gemm_bt<0><<<g3, 256, 0, stream>>>(CTX, Wout, out_b_loc, out, M, EE, EE);
  }

  // 5) cls output rows
  gemv2<<<512, 256, 0, stream>>>(ctxg, EE, out_w_cls, out_b_cls,
                                 out, (size_t)SS * EE, EE, EE);
}

// Round 7
// 132.029 us; speedup vs baseline: 3.4745x; 1.0091x over previous
//
#include <hip/hip_runtime.h>

// Problem constants: B=2, S=2048, E=1024, H=16, D=64, WIN=16
#define BB 2
#define SS 2048
#define EE 1024
#define HH 16
#define DD 64
#define NY 5120   // merged projection output cols: [Kcls|Vcls|Qloc|Kloc|Vloc]

typedef __attribute__((ext_vector_type(8))) short short8;
typedef __attribute__((ext_vector_type(4))) float f32x4;

__device__ __forceinline__ float bf2f(unsigned short u) {
  union { unsigned int i; float f; } v; v.i = ((unsigned int)u) << 16; return v.f;
}
__device__ __forceinline__ unsigned short f2bf(float f) {
  unsigned int u = __float_as_uint(f);
  u += 0x7fff + ((u >> 16) & 1);   // RNE
  return (unsigned short)(u >> 16);
}
__device__ __forceinline__ void gload_lds16(const void* g, void* l) {
  __builtin_amdgcn_global_load_lds(
      (const __attribute__((address_space(1))) void*)g,
      (__attribute__((address_space(3))) void*)l, 16, 0, 0);
}

// ---------------- fused f32->bf16 casts + q_cls GEMV (one launch) ----------------
__global__ void cast_all(const float* __restrict__ s0, unsigned short* __restrict__ d0,
                         const float* __restrict__ s1, unsigned short* __restrict__ d1,
                         const float* __restrict__ s2, unsigned short* __restrict__ d2,
                         const float* __restrict__ s3, unsigned short* __restrict__ d3,
                         const float* __restrict__ in_w_cls,
                         const float* __restrict__ in_b_cls,
                         float* __restrict__ qcls) {
  int b = blockIdx.x;
  if (b >= 10240) {   // q_cls GEMV: 512 blocks x 4 rows
    int gw = (b - 10240) * 4 + (threadIdx.x >> 6);
    int lane = threadIdx.x & 63;
    int bb = gw >> 10, n = gw & 1023;
    const float* x = s0 + (size_t)bb * SS * EE;
    const float* w = in_w_cls + (size_t)n * EE;
    float s = 0.0f;
    for (int k = lane; k < EE; k += 64) s += x[k] * w[k];
    for (int o = 32; o; o >>= 1) s += __shfl_xor(s, o);
    if (lane == 0) qcls[bb * EE + n] = s + in_b_cls[n];
    return;
  }
  const float* s; unsigned short* d; int idx;
  if (b < 4096)      { s = s0; d = d0; idx = b; }
  else if (b < 6144) { s = s1; d = d1; idx = b - 4096; }
  else if (b < 9216) { s = s2; d = d2; idx = b - 6144; }
  else               { s = s3; d = d3; idx = b - 9216; }
  int i = (idx * 256 + threadIdx.x) * 4;
  float4 v = *reinterpret_cast<const float4*>(s + i);
  ushort4 o;
  o.x = f2bf(v.x); o.y = f2bf(v.y); o.z = f2bf(v.z); o.w = f2bf(v.w);
  *reinterpret_cast<ushort4*>(d + i) = o;
}

// ================= 8-phase 256x320 projection GEMM (early-staged, swapped epilogue) ====
// Y[4096][5120] = Xbf[4096][1024] @ W[5120][1024]^T + bias
// 512 thr = 8 waves (2M x 4N), per-wave 128x80 (acc 8x5), BK=64, 16 K-tiles.
// t+1 staging fully issued in phases 0-1 -> seam vmcnt(0) has >=2 phases of cover.
// MFMA operands swapped so each lane holds 4 consecutive COLS -> ushort4 C-stores.
#define SBAR __builtin_amdgcn_sched_barrier(0)
#define RAWBAR do { SBAR; __builtin_amdgcn_s_barrier(); SBAR; } while (0)
#define WAITVM0 do { asm volatile("s_waitcnt vmcnt(0)" ::: "memory"); SBAR; } while (0)
#define LGKM0 do { asm volatile("s_waitcnt lgkmcnt(0)" ::: "memory"); SBAR; } while (0)

#define MFMA20(MH)                                                                   \
  _Pragma("unroll")                                                                  \
  for (int m = 0; m < 4; ++m)                                                        \
    _Pragma("unroll")                                                                \
    for (int n = 0; n < 5; ++n)                                                      \
      acc[(MH) * 4 + m][n] = __builtin_amdgcn_mfma_f32_16x16x32_bf16(                \
          bfr[n], afr[m], acc[(MH) * 4 + m][n], 0, 0, 0);

__global__ __launch_bounds__(512, 2)
void gemm8p(const unsigned short* __restrict__ Ag,   // [4096][1024]
            const unsigned short* __restrict__ Bg,   // [5120][1024]
            const float* __restrict__ bcls,
            const float* __restrict__ bloc,
            unsigned short* __restrict__ Yout) {     // [4096][5120]
  __shared__ unsigned short As2[2][256][64];   // 64 KiB
  __shared__ unsigned short Bs2[2][320][64];   // 80 KiB
  char* ldsA = (char*)As2;
  char* ldsB = (char*)Bs2;

  const int tid = threadIdx.x;
  const int wid = tid >> 6;
  const int lane = tid & 63;
  const int wm = wid >> 2;     // 0..1 -> 128-row slice
  const int wn = wid & 3;      // 0..3 -> 80-col slice
  const int rl = lane & 15;
  const int g4 = lane >> 4;

  int bid = blockIdx.x;
  bid = (bid & 7) * 32 + (bid >> 3);     // XCD swizzle, bijective (256 = 8*32)
  const int tileM = (bid & 15) * 256;
  const int tileN = (bid >> 4) * 320;

  f32x4 acc[8][5] = {};
  short8 afr[4], bfr[5];

  auto SA = [&](int c, int kk, int i) {
    int flat = i * 8192 + tid * 16;
    int row = flat >> 7;
    int colb = (flat & 127) ^ ((row & 7) << 4);
    gload_lds16(Ag + (size_t)(tileM + row) * 1024 + kk + (colb >> 1),
                ldsA + c * 32768 + i * 8192 + wid * 1024);
  };
  auto SB = [&](int c, int kk, int j) {
    int flat = j * 8192 + tid * 16;
    int row = flat >> 7;
    int colb = (flat & 127) ^ ((row & 7) << 4);
    gload_lds16(Bg + (size_t)(tileN + row) * 1024 + kk + (colb >> 1),
                ldsB + c * 40960 + j * 8192 + wid * 1024);
  };
  auto DSA = [&](int c, int mh, int kh) {
#pragma unroll
    for (int m = 0; m < 4; ++m) {
      int row = wm * 128 + mh * 64 + m * 16 + rl;
      const char* base = ldsA + c * 32768 + row * 128;
      afr[m] = *(const short8*)(base + ((kh * 64 + g4 * 16) ^ ((row & 7) << 4)));
    }
  };
  auto DSB = [&](int c, int kh) {
#pragma unroll
    for (int n = 0; n < 5; ++n) {
      int row = wn * 80 + n * 16 + rl;
      const char* base = ldsB + c * 40960 + row * 128;
      bfr[n] = *(const short8*)(base + ((kh * 64 + g4 * 16) ^ ((row & 7) << 4)));
    }
  };

  // prologue: tile 0 -> buf0
  SA(0, 0, 0); SA(0, 0, 1); SA(0, 0, 2); SA(0, 0, 3);
  SB(0, 0, 0); SB(0, 0, 1); SB(0, 0, 2); SB(0, 0, 3); SB(0, 0, 4);
  WAITVM0;
  RAWBAR;

#pragma unroll 1
  for (int t = 0; t < 16; ++t) {
    const int c = t & 1;
    const int kk = (t + 1) * 64;
    const bool st = (t < 15);
    // phase 0: (mh0, kh0) + stage t+1 B (5 issues)
    DSB(c, 0); DSA(c, 0, 0);
    if (st) { SB(c ^ 1, kk, 0); SB(c ^ 1, kk, 1); SB(c ^ 1, kk, 2); SB(c ^ 1, kk, 3); SB(c ^ 1, kk, 4); }
    RAWBAR; LGKM0;
    __builtin_amdgcn_s_setprio(1); MFMA20(0); __builtin_amdgcn_s_setprio(0);
    RAWBAR;
    // phase 1: (mh1, kh0) + stage t+1 A (4 issues)
    DSA(c, 1, 0);
    if (st) { SA(c ^ 1, kk, 0); SA(c ^ 1, kk, 1); SA(c ^ 1, kk, 2); SA(c ^ 1, kk, 3); }
    RAWBAR; LGKM0;
    __builtin_amdgcn_s_setprio(1); MFMA20(1); __builtin_amdgcn_s_setprio(0);
    RAWBAR;
    // phase 2: (mh0, kh1)
    DSB(c, 1); DSA(c, 0, 1);
    RAWBAR; LGKM0;
    __builtin_amdgcn_s_setprio(1); MFMA20(0); __builtin_amdgcn_s_setprio(0);
    RAWBAR;
    // phase 3: (mh1, kh1); seam drain covered by >=2 phases since last issue
    DSA(c, 1, 1);
    RAWBAR; LGKM0;
    __builtin_amdgcn_s_setprio(1); MFMA20(1); __builtin_amdgcn_s_setprio(0);
    if (st) WAITVM0;
    RAWBAR;
  }

  // epilogue (swapped layout): lane holds 4 consecutive cols ->
  // row = tileM + wm*128 + m*16 + rl ; col = tileN + wn*80 + n*16 + g4*4 + r
  float4 bv4[5];
#pragma unroll
  for (int n = 0; n < 5; ++n) {
    int gc = tileN + wn * 80 + n * 16 + g4 * 4;
    bv4[n] = *(const float4*)((gc < 2048) ? &bcls[1024 + gc] : &bloc[gc - 2048]);
  }
#pragma unroll
  for (int m = 0; m < 8; ++m) {
    int gr = tileM + wm * 128 + m * 16 + rl;
    unsigned short* yrow = Yout + (size_t)gr * NY + tileN + wn * 80 + g4 * 4;
#pragma unroll
    for (int n = 0; n < 5; ++n) {
      ushort4 o;
      o.x = f2bf(acc[m][n][0] + bv4[n].x);
      o.y = f2bf(acc[m][n][1] + bv4[n].y);
      o.z = f2bf(acc[m][n][2] + bv4[n].z);
      o.w = f2bf(acc[m][n][3] + bv4[n].w);
      *(ushort4*)(yrow + n * 16) = o;
    }
  }
}

// ---------------- 128x128 2-phase GEMM (out-proj only) ----------------
template <int OUT_BF16>
__global__ __launch_bounds__(256, 4)
void gemm_bt(const unsigned short* __restrict__ A,
             const unsigned short* __restrict__ B,
             const float* __restrict__ bias0,
             void* __restrict__ C, int M, int N, int K) {
  __shared__ unsigned short As[2][128 * 32];
  __shared__ unsigned short Bs[2][128 * 32];
  const int tid = threadIdx.x;
  const int wid = tid >> 6;
  const int lane = tid & 63;

  const int nx = gridDim.x;
  int bid = blockIdx.y * nx + blockIdx.x;
  const int nwg = nx * gridDim.y;
  if ((nwg & 7) == 0) { int c = nwg >> 3; bid = (bid & 7) * c + (bid >> 3); }
  const int tileM = (bid % nx) * 128;
  const int tileN = (bid / nx) * 128;

  const int wm = (wid >> 1) * 64;
  const int wn = (wid & 1) * 64;
  const int rl = lane & 15;
  const int kc = (lane >> 4) * 8;

  f32x4 acc[4][4] = {};

  const int srow = tid >> 2;
  const int scol = (tid & 3) * 8;
  const unsigned short* gA = A + (size_t)(tileM + srow) * K + scol;
  const unsigned short* gB = B + (size_t)(tileN + srow) * K + scol;
  char* lA = (char*)As + wid * 1024;
  char* lB = (char*)Bs + wid * 1024;

  auto STAGE = [&](int buf, int k0) {
    gload_lds16(gA + k0, lA + buf * 8192);
    gload_lds16(gA + (size_t)64 * K + k0, lA + buf * 8192 + 4096);
    gload_lds16(gB + k0, lB + buf * 8192);
    gload_lds16(gB + (size_t)64 * K + k0, lB + buf * 8192 + 4096);
  };
  auto COMPUTE = [&](int buf) {
    const unsigned short* as = As[buf];
    const unsigned short* bs = Bs[buf];
    short8 af[4], bfg[4];
#pragma unroll
    for (int mi = 0; mi < 4; ++mi)
      af[mi] = *reinterpret_cast<const short8*>(&as[(wm + mi * 16 + rl) * 32 + kc]);
#pragma unroll
    for (int ni = 0; ni < 4; ++ni)
      bfg[ni] = *reinterpret_cast<const short8*>(&bs[(wn + ni * 16 + rl) * 32 + kc]);
#pragma unroll
    for (int mi = 0; mi < 4; ++mi)
#pragma unroll
      for (int ni = 0; ni < 4; ++ni)
        acc[mi][ni] = __builtin_amdgcn_mfma_f32_16x16x32_bf16(
            af[mi], bfg[ni], acc[mi][ni], 0, 0, 0);
  };

  STAGE(0, 0);
  asm volatile("s_waitcnt vmcnt(0)" ::: "memory");
  __syncthreads();
  int cur = 0;
  for (int k0 = 32; k0 < K; k0 += 32) {
    STAGE(cur ^ 1, k0);
    COMPUTE(cur);
    asm volatile("s_waitcnt vmcnt(0)" ::: "memory");
    __syncthreads();
    cur ^= 1;
  }
  COMPUTE(cur);

  const int crow0 = (lane >> 4) * 4;
  const int ccol = lane & 15;
#pragma unroll
  for (int mi = 0; mi < 4; ++mi)
#pragma unroll
    for (int ni = 0; ni < 4; ++ni) {
      int gc = tileN + wn + ni * 16 + ccol;
      float bv = bias0[gc];
#pragma unroll
      for (int r = 0; r < 4; ++r) {
        int gr = tileM + wm + mi * 16 + crow0 + r;
        if (gr < M) {
          float v = acc[mi][ni][r] + bv;
          if (OUT_BF16)
            ((unsigned short*)C)[(size_t)gr * N + gc] = f2bf(v);
          else
            ((float*)C)[(size_t)gr * N + gc] = v;
        }
      }
    }
}

// ---------------- fused attention: local (x<16) + global partials (x>=16) ----------------
#define QBL 128
#define VT_PAD 168
#define P_PAD 72
__global__ __launch_bounds__(256, 2)
void attn_fused(const float* __restrict__ qcls,
                const unsigned short* __restrict__ Y,
                float* __restrict__ part,
                unsigned short* __restrict__ CTX) {
  const int h = blockIdx.y, b = blockIdx.z;
  const int tid = threadIdx.x, wid = tid >> 6, lane = tid & 63;

  __shared__ unsigned short Vt[64][VT_PAD];
  __shared__ unsigned short Pl[4][32][P_PAD];
  __shared__ float qf[64];
  __shared__ float ps[256];
  __shared__ float red[8];
  __shared__ float pacc[4][64];

  if (blockIdx.x >= 16) {
    // ===== global (cls) attention partial, key-chunk kc =====
    const int kc = blockIdx.x - 16;
    if (tid < 64) qf[tid] = qcls[b * EE + h * DD + tid];
    __syncthreads();

    int s = kc * 256 + tid;
    const short8* k8 = (const short8*)(Y + (size_t)(b * SS + s) * NY + h * DD);
    float dot = 0.0f;
#pragma unroll
    for (int i = 0; i < 8; ++i) {
      short8 kv = k8[i];
#pragma unroll
      for (int e = 0; e < 8; ++e) dot += qf[i * 8 + e] * bf2f((unsigned short)kv[e]);
    }
    dot *= 0.125f;

    float mx = dot;
    for (int o = 32; o; o >>= 1) mx = fmaxf(mx, __shfl_xor(mx, o));
    if ((tid & 63) == 0) red[tid >> 6] = mx;
    __syncthreads();
    float M = fmaxf(fmaxf(red[0], red[1]), fmaxf(red[2], red[3]));

    float p = __expf(dot - M);
    ps[tid] = p;
    float l = p;
    for (int o = 32; o; o >>= 1) l += __shfl_xor(l, o);
    if ((tid & 63) == 0) red[4 + (tid >> 6)] = l;
    __syncthreads();
    float L = red[4] + red[5] + red[6] + red[7];

    int g = tid >> 6, d = tid & 63;
    float acc = 0.0f;
    for (int sl = g; sl < 256; sl += 4)
      acc += ps[sl] * bf2f(Y[(size_t)(b * SS + kc * 256 + sl) * NY + 1024 + h * DD + d]);
    pacc[g][d] = acc;
    __syncthreads();
    if (g == 0) {
      float a = pacc[0][d] + pacc[1][d] + pacc[2][d] + pacc[3][d];
      float* pp = part + ((size_t)(b * HH + h) * 8 + kc) * 66;
      if (d == 0) { pp[0] = M; pp[1] = L; }
      pp[2 + d] = a;
    }
    return;
  }

  // ===== local attention via MFMA =====
  const int s0 = blockIdx.x * QBL;
  const int rl = lane & 15, g = lane >> 4;

  for (int task = tid; task < 640; task += 256) {
    int kp = task % 80, ch = task / 80;
    int k0 = kp * 2;
    int kg0 = min(max(s0 - 16 + k0, 0), SS - 1);
    int kg1 = min(max(s0 - 16 + k0 + 1, 0), SS - 1);
    short8 a = *(const short8*)&Y[(size_t)(b * SS + kg0) * NY + 4096 + h * DD + ch * 8];
    short8 bv = *(const short8*)&Y[(size_t)(b * SS + kg1) * NY + 4096 + h * DD + ch * 8];
#pragma unroll
    for (int e = 0; e < 8; ++e) {
      unsigned int w = (unsigned int)(unsigned short)a[e] |
                       ((unsigned int)(unsigned short)bv[e] << 16);
      *(unsigned int*)&Vt[ch * 8 + e][k0] = w;
    }
  }
  __syncthreads();

  const int qb = s0 + wid * 32;
  const int kb = qb - 16;

  short8 ak[4][2];
#pragma unroll
  for (int kt = 0; kt < 4; ++kt) {
    int kg = min(max(kb + kt * 16 + rl, 0), SS - 1);
    const unsigned short* kr = &Y[(size_t)(b * SS + kg) * NY + 3072 + h * DD + g * 8];
#pragma unroll
    for (int ks = 0; ks < 2; ++ks) ak[kt][ks] = *(const short8*)(kr + ks * 32);
  }
  short8 bq[2][2];
#pragma unroll
  for (int cc = 0; cc < 2; ++cc) {
    const unsigned short* qr = &Y[(size_t)(b * SS + qb + cc * 16 + rl) * NY + 2048 + h * DD + g * 8];
#pragma unroll
    for (int ks = 0; ks < 2; ++ks) bq[cc][ks] = *(const short8*)(qr + ks * 32);
  }

  f32x4 accs[4][2] = {};
#pragma unroll
  for (int kt = 0; kt < 4; ++kt)
#pragma unroll
    for (int cc = 0; cc < 2; ++cc)
#pragma unroll
      for (int ks = 0; ks < 2; ++ks)
        accs[kt][cc] = __builtin_amdgcn_mfma_f32_16x16x32_bf16(
            ak[kt][ks], bq[cc][ks], accs[kt][cc], 0, 0, 0);

  float mrow[2] = {-3e38f, -3e38f};
#pragma unroll
  for (int kt = 0; kt < 4; ++kt)
#pragma unroll
    for (int cc = 0; cc < 2; ++cc)
#pragma unroll
      for (int r = 0; r < 4; ++r) {
        int kg = kb + kt * 16 + 4 * g + r;
        int qg = qb + cc * 16 + rl;
        bool valid = (kg >= qg - 16) && (kg <= qg + 16) && (kg >= 1) && (kg < SS);
        float v = valid ? accs[kt][cc][r] : -3e38f;
        accs[kt][cc][r] = v;
        mrow[cc] = fmaxf(mrow[cc], v);
      }
#pragma unroll
  for (int cc = 0; cc < 2; ++cc) {
    float m = mrow[cc];
    m = fmaxf(m, __shfl_xor(m, 16));
    m = fmaxf(m, __shfl_xor(m, 32));
    mrow[cc] = m;
  }

  float zrow[2] = {0.0f, 0.0f};
#pragma unroll
  for (int cc = 0; cc < 2; ++cc)
#pragma unroll
    for (int kt = 0; kt < 4; ++kt) {
      ushort4 pw;
#pragma unroll
      for (int r = 0; r < 4; ++r) {
        float p = __expf((accs[kt][cc][r] - mrow[cc]) * 0.125f);
        zrow[cc] += p;
        ((unsigned short*)&pw)[r] = f2bf(p);
      }
      *(ushort4*)&Pl[wid][cc * 16 + rl][kt * 16 + 4 * g] = pw;
    }
#pragma unroll
  for (int cc = 0; cc < 2; ++cc) {
    float z = zrow[cc];
    z += __shfl_xor(z, 16);
    z += __shfl_xor(z, 32);
    zrow[cc] = 1.0f / z;
  }

  f32x4 accp[4][2] = {};
#pragma unroll
  for (int ks = 0; ks < 2; ++ks) {
    short8 bp[2];
#pragma unroll
    for (int cc = 0; cc < 2; ++cc)
      bp[cc] = *(const short8*)&Pl[wid][cc * 16 + rl][ks * 32 + g * 8];
#pragma unroll
    for (int mt = 0; mt < 4; ++mt) {
      short8 av = *(const short8*)&Vt[mt * 16 + rl][wid * 32 + ks * 32 + g * 8];
#pragma unroll
      for (int cc = 0; cc < 2; ++cc)
        accp[mt][cc] = __builtin_amdgcn_mfma_f32_16x16x32_bf16(
            av, bp[cc], accp[mt][cc], 0, 0, 0);
    }
  }

#pragma unroll
  for (int mt = 0; mt < 4; ++mt)
#pragma unroll
    for (int cc = 0; cc < 2; ++cc) {
      int token = qb + cc * 16 + rl;
      if (token == 0) {
        *(ushort4*)&CTX[(size_t)(b * SS) * EE + h * DD + mt * 16 + 4 * g] = ushort4{0, 0, 0, 0};
        continue;
      }
      ushort4 o;
#pragma unroll
      for (int r = 0; r < 4; ++r)
        ((unsigned short*)&o)[r] = f2bf(accp[mt][cc][r] * zrow[cc]);
      *(ushort4*)&CTX[(size_t)(b * SS + token) * EE + h * DD + mt * 16 + 4 * g] = o;
    }
}

// ---------------- cls output rows: combine partials + GEMV (one launch) ----------------
__global__ void gemv_cls(const float* __restrict__ part,
                         const float* __restrict__ Wc,     // out_w_cls [1024][1024]
                         const float* __restrict__ bc,
                         float* __restrict__ out) {
  __shared__ float ctx[EE];
  __shared__ float u[HH][8];
  const int b = blockIdx.x >> 8;
  const int tid = threadIdx.x;
  const float* pb = part + (size_t)b * HH * 8 * 66;
  if (tid < HH) {
    const float* pp = pb + tid * 8 * 66;
    float M = -1e30f;
#pragma unroll
    for (int i = 0; i < 8; ++i) M = fmaxf(M, pp[i * 66]);
    float Z = 0.0f, w[8];
#pragma unroll
    for (int i = 0; i < 8; ++i) { w[i] = __expf(pp[i * 66] - M); Z += w[i] * pp[i * 66 + 1]; }
#pragma unroll
    for (int i = 0; i < 8; ++i) u[tid][i] = w[i] / Z;
  }
  __syncthreads();
  for (int k = tid; k < EE; k += 256) {
    int hh = k >> 6, d = k & 63;
    const float* pp = pb + hh * 8 * 66 + 2 + d;
    float a = 0.0f;
#pragma unroll
    for (int i = 0; i < 8; ++i) a += u[hh][i] * pp[i * 66];
    ctx[k] = a;
  }
  __syncthreads();
  int n = (blockIdx.x & 255) * 4 + (tid >> 6);
  int lane = tid & 63;
  const float* w = Wc + (size_t)n * EE;
  float s = 0.0f;
  for (int k = lane; k < EE; k += 64) s += ctx[k] * w[k];
  for (int o = 32; o; o >>= 1) s += __shfl_xor(s, o);
  if (lane == 0) out[(size_t)b * SS * EE + n] = s + bc[n];
}

extern "C" void kernel_launch(void* const* d_in, const int* in_sizes, int n_in,
                              void* d_out, int out_size, void* d_ws, size_t ws_size,
                              hipStream_t stream) {
  const float* hs        = (const float*)d_in[0];
  const float* in_w_cls  = (const float*)d_in[1];
  const float* in_b_cls  = (const float*)d_in[2];
  const float* out_w_cls = (const float*)d_in[3];
  const float* out_b_cls = (const float*)d_in[4];
  const float* in_w_loc  = (const float*)d_in[5];
  const float* in_b_loc  = (const float*)d_in[6];
  const float* out_w_loc = (const float*)d_in[7];
  const float* out_b_loc = (const float*)d_in[8];
  float* out = (float*)d_out;

  const int M = BB * SS;  // 4096
  char* ws = (char*)d_ws;
  size_t off = 0;
  auto alloc = [&](size_t bytes) { char* p = ws + off; off += (bytes + 255) & ~(size_t)255; return p; };
  unsigned short* Xbf  = (unsigned short*)alloc((size_t)M * EE * 2);
  unsigned short* W    = (unsigned short*)alloc((size_t)NY * EE * 2);
  unsigned short* Wout = (unsigned short*)alloc((size_t)EE * EE * 2);
  unsigned short* Yb   = (unsigned short*)alloc((size_t)M * NY * 2);
  unsigned short* CTX  = (unsigned short*)alloc((size_t)M * EE * 2);
  float* qcls = (float*)alloc(2 * EE * 4);
  float* part = (float*)alloc((size_t)BB * HH * 8 * 66 * 4);

  // 1) fused casts + q_cls GEMV
  cast_all<<<10752, 256, 0, stream>>>(
      hs, Xbf,
      in_w_cls + (size_t)EE * EE, W,
      in_w_loc, W + (size_t)2048 * EE,
      out_w_loc, Wout,
      in_w_cls, in_b_cls, qcls);

  // 2) merged projection GEMM (8-phase, 256x320 tiles, 256 blocks = 1 round)
  gemm8p<<<256, 512, 0, stream>>>(Xbf, W, in_b_cls, in_b_loc, Yb);

  // 3) fused attention (local MFMA + cls partials)
  attn_fused<<<dim3(24, HH, BB), 256, 0, stream>>>(qcls, Yb, part, CTX);

  // 4) local output projection (writes all rows of d_out; rows 0,2048 fixed next)
  {
    dim3 g3(M / 128, EE / 128);
    gemm_bt<0><<<g3, 256, 0, stream>>>(CTX, Wout, out_b_loc, out, M, EE, EE);
  }

  // 5) cls output rows (combine + GEMV fused)
  gemv_cls<<<512, 256, 0, stream>>>(part, out_w_cls, out_b_cls, out);
}

// Round 8
// 130.844 us; speedup vs baseline: 3.5060x; 1.0091x over previous
//
#include <hip/hip_runtime.h>

// Problem constants: B=2, S=2048, E=1024, H=16, D=64, WIN=16
#define BB 2
#define SS 2048
#define EE 1024
#define HH 16
#define DD 64
#define NY 5120   // merged projection output cols: [Kcls|Vcls|Qloc|Kloc|Vloc]

typedef __attribute__((ext_vector_type(8))) short short8;
typedef __attribute__((ext_vector_type(4))) float f32x4;

__device__ __forceinline__ float bf2f(unsigned short u) {
  union { unsigned int i; float f; } v; v.i = ((unsigned int)u) << 16; return v.f;
}
__device__ __forceinline__ unsigned short f2bf(float f) {
  unsigned int u = __float_as_uint(f);
  u += 0x7fff + ((u >> 16) & 1);   // RNE
  return (unsigned short)(u >> 16);
}
__device__ __forceinline__ void gload_lds16(const void* g, void* l) {
  __builtin_amdgcn_global_load_lds(
      (const __attribute__((address_space(1))) void*)g,
      (__attribute__((address_space(3))) void*)l, 16, 0, 0);
}

// ---------------- fused f32->bf16 casts + q_cls GEMV (one launch) ----------------
__global__ void cast_all(const float* __restrict__ s0, unsigned short* __restrict__ d0,
                         const float* __restrict__ s1, unsigned short* __restrict__ d1,
                         const float* __restrict__ s2, unsigned short* __restrict__ d2,
                         const float* __restrict__ s3, unsigned short* __restrict__ d3,
                         const float* __restrict__ in_w_cls,
                         const float* __restrict__ in_b_cls,
                         float* __restrict__ qcls) {
  int b = blockIdx.x;
  if (b >= 10240) {   // q_cls GEMV: 512 blocks x 4 rows
    int gw = (b - 10240) * 4 + (threadIdx.x >> 6);
    int lane = threadIdx.x & 63;
    int bb = gw >> 10, n = gw & 1023;
    const float* x = s0 + (size_t)bb * SS * EE;
    const float* w = in_w_cls + (size_t)n * EE;
    float s = 0.0f;
    for (int k = lane; k < EE; k += 64) s += x[k] * w[k];
    for (int o = 32; o; o >>= 1) s += __shfl_xor(s, o);
    if (lane == 0) qcls[bb * EE + n] = s + in_b_cls[n];
    return;
  }
  const float* s; unsigned short* d; int idx;
  if (b < 4096)      { s = s0; d = d0; idx = b; }
  else if (b < 6144) { s = s1; d = d1; idx = b - 4096; }
  else if (b < 9216) { s = s2; d = d2; idx = b - 6144; }
  else               { s = s3; d = d3; idx = b - 9216; }
  int i = (idx * 256 + threadIdx.x) * 4;
  float4 v = *reinterpret_cast<const float4*>(s + i);
  ushort4 o;
  o.x = f2bf(v.x); o.y = f2bf(v.y); o.z = f2bf(v.z); o.w = f2bf(v.w);
  *reinterpret_cast<ushort4*>(d + i) = o;
}

// ================= 8-phase 256x320 projection GEMM — COUNTED vmcnt pipeline ======
// Y[4096][5120] = Xbf[4096][1024] @ W[5120][1024]^T + bias
// 512 thr = 8 waves (2M x 4N), per-wave 128x80 (acc 8x5), BK=64, 16 K-tiles.
// Staging of tile t+1 (into buf c^1, no WAR: reads are from buf c):
//   ph0: B0,B1,B2   ph1: B3,B4,A0,A2   ph2: A1,A3
// Reads: ph0 needs B+A0+A2 (seam wait vmcnt(2): newest 2 = A1',A3' may fly);
//        ph1 needs A1,A3 (end-ph0 wait vmcnt(3): newest 3 = B' may fly);
//        ph2/ph3 re-read same slabs (64-full-row slabs) -> no wait.
// No vmcnt(0) in the main loop (T4); every waited load has >=2 phases of cover.
#define SBAR __builtin_amdgcn_sched_barrier(0)
#define RAWBAR do { SBAR; __builtin_amdgcn_s_barrier(); SBAR; } while (0)
#define WAITVM(n) do { asm volatile("s_waitcnt vmcnt(" #n ")" ::: "memory"); SBAR; } while (0)
#define LGKM0 do { asm volatile("s_waitcnt lgkmcnt(0)" ::: "memory"); SBAR; } while (0)

#define MFMA20(MH)                                                                   \
  _Pragma("unroll")                                                                  \
  for (int m = 0; m < 4; ++m)                                                        \
    _Pragma("unroll")                                                                \
    for (int n = 0; n < 5; ++n)                                                      \
      acc[(MH) * 4 + m][n] = __builtin_amdgcn_mfma_f32_16x16x32_bf16(                \
          bfr[n], afr[m], acc[(MH) * 4 + m][n], 0, 0, 0);

__global__ __launch_bounds__(512, 2)
void gemm8p(const unsigned short* __restrict__ Ag,   // [4096][1024]
            const unsigned short* __restrict__ Bg,   // [5120][1024]
            const float* __restrict__ bcls,
            const float* __restrict__ bloc,
            unsigned short* __restrict__ Yout) {     // [4096][5120]
  __shared__ unsigned short As2[2][256][64];   // 64 KiB
  __shared__ unsigned short Bs2[2][320][64];   // 80 KiB
  char* ldsA = (char*)As2;
  char* ldsB = (char*)Bs2;

  const int tid = threadIdx.x;
  const int wid = tid >> 6;
  const int lane = tid & 63;
  const int wm = wid >> 2;     // 0..1 -> 128-row slice (reads A slabs {2wm, 2wm+1} only)
  const int wn = wid & 3;      // 0..3 -> 80-col slice
  const int rl = lane & 15;
  const int g4 = lane >> 4;

  int bid = blockIdx.x;
  bid = (bid & 7) * 32 + (bid >> 3);     // XCD swizzle, bijective (256 = 8*32)
  const int tileM = (bid & 15) * 256;
  const int tileN = (bid >> 4) * 320;

  f32x4 acc[8][5] = {};
  short8 afr[4], bfr[5];

  auto SA = [&](int c, int kk, int i) {   // A slab i = rows i*64..i*64+63 (8 KB)
    int flat = i * 8192 + tid * 16;
    int row = flat >> 7;
    int colb = (flat & 127) ^ ((row & 7) << 4);
    gload_lds16(Ag + (size_t)(tileM + row) * 1024 + kk + (colb >> 1),
                ldsA + c * 32768 + i * 8192 + wid * 1024);
  };
  auto SB = [&](int c, int kk, int j) {   // B slab j = rows j*64..j*64+63 (8 KB)
    int flat = j * 8192 + tid * 16;
    int row = flat >> 7;
    int colb = (flat & 127) ^ ((row & 7) << 4);
    gload_lds16(Bg + (size_t)(tileN + row) * 1024 + kk + (colb >> 1),
                ldsB + c * 40960 + j * 8192 + wid * 1024);
  };
  auto DSA = [&](int c, int mh, int kh) {
#pragma unroll
    for (int m = 0; m < 4; ++m) {
      int row = wm * 128 + mh * 64 + m * 16 + rl;
      const char* base = ldsA + c * 32768 + row * 128;
      afr[m] = *(const short8*)(base + ((kh * 64 + g4 * 16) ^ ((row & 7) << 4)));
    }
  };
  auto DSB = [&](int c, int kh) {
#pragma unroll
    for (int n = 0; n < 5; ++n) {
      int row = wn * 80 + n * 16 + rl;
      const char* base = ldsB + c * 40960 + row * 128;
      bfr[n] = *(const short8*)(base + ((kh * 64 + g4 * 16) ^ ((row & 7) << 4)));
    }
  };

  // prologue: tile 0 -> buf0, full drain
  SB(0, 0, 0); SB(0, 0, 1); SB(0, 0, 2); SB(0, 0, 3); SB(0, 0, 4);
  SA(0, 0, 0); SA(0, 0, 1); SA(0, 0, 2); SA(0, 0, 3);
  WAITVM(0);
  RAWBAR;

#pragma unroll 1
  for (int t = 0; t < 16; ++t) {
    const int c = t & 1;
    const int kk = (t + 1) * 64;
    const bool st = (t < 15);
    // phase 0: (mh0, kh0) | stage B0-2(t+1)
    DSB(c, 0); DSA(c, 0, 0);
    if (st) { SB(c ^ 1, kk, 0); SB(c ^ 1, kk, 1); SB(c ^ 1, kk, 2); }
    RAWBAR; LGKM0;
    __builtin_amdgcn_s_setprio(1); MFMA20(0); __builtin_amdgcn_s_setprio(0);
    if (st) WAITVM(3); else WAITVM(0);   // A1,A3(t) landed; B'(t+1) may fly
    RAWBAR;
    // phase 1: (mh1, kh0) | stage B3,B4 + A0,A2 (t+1)
    DSA(c, 1, 0);
    if (st) { SB(c ^ 1, kk, 3); SB(c ^ 1, kk, 4); SA(c ^ 1, kk, 0); SA(c ^ 1, kk, 2); }
    RAWBAR; LGKM0;
    __builtin_amdgcn_s_setprio(1); MFMA20(1); __builtin_amdgcn_s_setprio(0);
    RAWBAR;
    // phase 2: (mh0, kh1) | stage A1,A3 (t+1)
    DSB(c, 1); DSA(c, 0, 1);
    if (st) { SA(c ^ 1, kk, 1); SA(c ^ 1, kk, 3); }
    RAWBAR; LGKM0;
    __builtin_amdgcn_s_setprio(1); MFMA20(0); __builtin_amdgcn_s_setprio(0);
    RAWBAR;
    // phase 3: (mh1, kh1) | seam: counted wait for B+A0+A2(t+1); A1',A3' may fly
    DSA(c, 1, 1);
    RAWBAR; LGKM0;
    __builtin_amdgcn_s_setprio(1); MFMA20(1); __builtin_amdgcn_s_setprio(0);
    if (st) WAITVM(2);
    RAWBAR;
  }

  // epilogue (swapped layout): lane holds 4 consecutive cols ->
  // row = tileM + wm*128 + m*16 + rl ; col = tileN + wn*80 + n*16 + g4*4 + r
  float4 bv4[5];
#pragma unroll
  for (int n = 0; n < 5; ++n) {
    int gc = tileN + wn * 80 + n * 16 + g4 * 4;
    bv4[n] = *(const float4*)((gc < 2048) ? &bcls[1024 + gc] : &bloc[gc - 2048]);
  }
#pragma unroll
  for (int m = 0; m < 8; ++m) {
    int gr = tileM + wm * 128 + m * 16 + rl;
    unsigned short* yrow = Yout + (size_t)gr * NY + tileN + wn * 80 + g4 * 4;
#pragma unroll
    for (int n = 0; n < 5; ++n) {
      ushort4 o;
      o.x = f2bf(acc[m][n][0] + bv4[n].x);
      o.y = f2bf(acc[m][n][1] + bv4[n].y);
      o.z = f2bf(acc[m][n][2] + bv4[n].z);
      o.w = f2bf(acc[m][n][3] + bv4[n].w);
      *(ushort4*)(yrow + n * 16) = o;
    }
  }
}

// ---------------- 128x128 2-phase GEMM (out-proj only) ----------------
template <int OUT_BF16>
__global__ __launch_bounds__(256, 4)
void gemm_bt(const unsigned short* __restrict__ A,
             const unsigned short* __restrict__ B,
             const float* __restrict__ bias0,
             void* __restrict__ C, int M, int N, int K) {
  __shared__ unsigned short As[2][128 * 32];
  __shared__ unsigned short Bs[2][128 * 32];
  const int tid = threadIdx.x;
  const int wid = tid >> 6;
  const int lane = tid & 63;

  const int nx = gridDim.x;
  int bid = blockIdx.y * nx + blockIdx.x;
  const int nwg = nx * gridDim.y;
  if ((nwg & 7) == 0) { int c = nwg >> 3; bid = (bid & 7) * c + (bid >> 3); }
  const int tileM = (bid % nx) * 128;
  const int tileN = (bid / nx) * 128;

  const int wm = (wid >> 1) * 64;
  const int wn = (wid & 1) * 64;
  const int rl = lane & 15;
  const int kc = (lane >> 4) * 8;

  f32x4 acc[4][4] = {};

  const int srow = tid >> 2;
  const int scol = (tid & 3) * 8;
  const unsigned short* gA = A + (size_t)(tileM + srow) * K + scol;
  const unsigned short* gB = B + (size_t)(tileN + srow) * K + scol;
  char* lA = (char*)As + wid * 1024;
  char* lB = (char*)Bs + wid * 1024;

  auto STAGE = [&](int buf, int k0) {
    gload_lds16(gA + k0, lA + buf * 8192);
    gload_lds16(gA + (size_t)64 * K + k0, lA + buf * 8192 + 4096);
    gload_lds16(gB + k0, lB + buf * 8192);
    gload_lds16(gB + (size_t)64 * K + k0, lB + buf * 8192 + 4096);
  };
  auto COMPUTE = [&](int buf) {
    const unsigned short* as = As[buf];
    const unsigned short* bs = Bs[buf];
    short8 af[4], bfg[4];
#pragma unroll
    for (int mi = 0; mi < 4; ++mi)
      af[mi] = *reinterpret_cast<const short8*>(&as[(wm + mi * 16 + rl) * 32 + kc]);
#pragma unroll
    for (int ni = 0; ni < 4; ++ni)
      bfg[ni] = *reinterpret_cast<const short8*>(&bs[(wn + ni * 16 + rl) * 32 + kc]);
#pragma unroll
    for (int mi = 0; mi < 4; ++mi)
#pragma unroll
      for (int ni = 0; ni < 4; ++ni)
        acc[mi][ni] = __builtin_amdgcn_mfma_f32_16x16x32_bf16(
            af[mi], bfg[ni], acc[mi][ni], 0, 0, 0);
  };

  STAGE(0, 0);
  asm volatile("s_waitcnt vmcnt(0)" ::: "memory");
  __syncthreads();
  int cur = 0;
  for (int k0 = 32; k0 < K; k0 += 32) {
    STAGE(cur ^ 1, k0);
    COMPUTE(cur);
    asm volatile("s_waitcnt vmcnt(0)" ::: "memory");
    __syncthreads();
    cur ^= 1;
  }
  COMPUTE(cur);

  const int crow0 = (lane >> 4) * 4;
  const int ccol = lane & 15;
#pragma unroll
  for (int mi = 0; mi < 4; ++mi)
#pragma unroll
    for (int ni = 0; ni < 4; ++ni) {
      int gc = tileN + wn + ni * 16 + ccol;
      float bv = bias0[gc];
#pragma unroll
      for (int r = 0; r < 4; ++r) {
        int gr = tileM + wm + mi * 16 + crow0 + r;
        if (gr < M) {
          float v = acc[mi][ni][r] + bv;
          if (OUT_BF16)
            ((unsigned short*)C)[(size_t)gr * N + gc] = f2bf(v);
          else
            ((float*)C)[(size_t)gr * N + gc] = v;
        }
      }
    }
}

// ---------------- fused attention: local (x<16) + global partials (x>=16) ----------------
#define QBL 128
#define VT_PAD 168
#define P_PAD 72
__global__ __launch_bounds__(256, 2)
void attn_fused(const float* __restrict__ qcls,
                const unsigned short* __restrict__ Y,
                float* __restrict__ part,
                unsigned short* __restrict__ CTX) {
  const int h = blockIdx.y, b = blockIdx.z;
  const int tid = threadIdx.x, wid = tid >> 6, lane = tid & 63;

  __shared__ unsigned short Vt[64][VT_PAD];
  __shared__ unsigned short Pl[4][32][P_PAD];
  __shared__ float qf[64];
  __shared__ float ps[256];
  __shared__ float red[8];
  __shared__ float pacc[4][64];

  if (blockIdx.x >= 16) {
    // ===== global (cls) attention partial, key-chunk kc =====
    const int kc = blockIdx.x - 16;
    if (tid < 64) qf[tid] = qcls[b * EE + h * DD + tid];
    __syncthreads();

    int s = kc * 256 + tid;
    const short8* k8 = (const short8*)(Y + (size_t)(b * SS + s) * NY + h * DD);
    float dot = 0.0f;
#pragma unroll
    for (int i = 0; i < 8; ++i) {
      short8 kv = k8[i];
#pragma unroll
      for (int e = 0; e < 8; ++e) dot += qf[i * 8 + e] * bf2f((unsigned short)kv[e]);
    }
    dot *= 0.125f;

    float mx = dot;
    for (int o = 32; o; o >>= 1) mx = fmaxf(mx, __shfl_xor(mx, o));
    if ((tid & 63) == 0) red[tid >> 6] = mx;
    __syncthreads();
    float M = fmaxf(fmaxf(red[0], red[1]), fmaxf(red[2], red[3]));

    float p = __expf(dot - M);
    ps[tid] = p;
    float l = p;
    for (int o = 32; o; o >>= 1) l += __shfl_xor(l, o);
    if ((tid & 63) == 0) red[4 + (tid >> 6)] = l;
    __syncthreads();
    float L = red[4] + red[5] + red[6] + red[7];

    int g = tid >> 6, d = tid & 63;
    float acc = 0.0f;
    for (int sl = g; sl < 256; sl += 4)
      acc += ps[sl] * bf2f(Y[(size_t)(b * SS + kc * 256 + sl) * NY + 1024 + h * DD + d]);
    pacc[g][d] = acc;
    __syncthreads();
    if (g == 0) {
      float a = pacc[0][d] + pacc[1][d] + pacc[2][d] + pacc[3][d];
      float* pp = part + ((size_t)(b * HH + h) * 8 + kc) * 66;
      if (d == 0) { pp[0] = M; pp[1] = L; }
      pp[2 + d] = a;
    }
    return;
  }

  // ===== local attention via MFMA =====
  const int s0 = blockIdx.x * QBL;
  const int rl = lane & 15, g = lane >> 4;

  for (int task = tid; task < 640; task += 256) {
    int kp = task % 80, ch = task / 80;
    int k0 = kp * 2;
    int kg0 = min(max(s0 - 16 + k0, 0), SS - 1);
    int kg1 = min(max(s0 - 16 + k0 + 1, 0), SS - 1);
    short8 a = *(const short8*)&Y[(size_t)(b * SS + kg0) * NY + 4096 + h * DD + ch * 8];
    short8 bv = *(const short8*)&Y[(size_t)(b * SS + kg1) * NY + 4096 + h * DD + ch * 8];
#pragma unroll
    for (int e = 0; e < 8; ++e) {
      unsigned int w = (unsigned int)(unsigned short)a[e] |
                       ((unsigned int)(unsigned short)bv[e] << 16);
      *(unsigned int*)&Vt[ch * 8 + e][k0] = w;
    }
  }
  __syncthreads();

  const int qb = s0 + wid * 32;
  const int kb = qb - 16;

  short8 ak[4][2];
#pragma unroll
  for (int kt = 0; kt < 4; ++kt) {
    int kg = min(max(kb + kt * 16 + rl, 0), SS - 1);
    const unsigned short* kr = &Y[(size_t)(b * SS + kg) * NY + 3072 + h * DD + g * 8];
#pragma unroll
    for (int ks = 0; ks < 2; ++ks) ak[kt][ks] = *(const short8*)(kr + ks * 32);
  }
  short8 bq[2][2];
#pragma unroll
  for (int cc = 0; cc < 2; ++cc) {
    const unsigned short* qr = &Y[(size_t)(b * SS + qb + cc * 16 + rl) * NY + 2048 + h * DD + g * 8];
#pragma unroll
    for (int ks = 0; ks < 2; ++ks) bq[cc][ks] = *(const short8*)(qr + ks * 32);
  }

  f32x4 accs[4][2] = {};
#pragma unroll
  for (int kt = 0; kt < 4; ++kt)
#pragma unroll
    for (int cc = 0; cc < 2; ++cc)
#pragma unroll
      for (int ks = 0; ks < 2; ++ks)
        accs[kt][cc] = __builtin_amdgcn_mfma_f32_16x16x32_bf16(
            ak[kt][ks], bq[cc][ks], accs[kt][cc], 0, 0, 0);

  float mrow[2] = {-3e38f, -3e38f};
#pragma unroll
  for (int kt = 0; kt < 4; ++kt)
#pragma unroll
    for (int cc = 0; cc < 2; ++cc)
#pragma unroll
      for (int r = 0; r < 4; ++r) {
        int kg = kb + kt * 16 + 4 * g + r;
        int qg = qb + cc * 16 + rl;
        bool valid = (kg >= qg - 16) && (kg <= qg + 16) && (kg >= 1) && (kg < SS);
        float v = valid ? accs[kt][cc][r] : -3e38f;
        accs[kt][cc][r] = v;
        mrow[cc] = fmaxf(mrow[cc], v);
      }
#pragma unroll
  for (int cc = 0; cc < 2; ++cc) {
    float m = mrow[cc];
    m = fmaxf(m, __shfl_xor(m, 16));
    m = fmaxf(m, __shfl_xor(m, 32));
    mrow[cc] = m;
  }

  float zrow[2] = {0.0f, 0.0f};
#pragma unroll
  for (int cc = 0; cc < 2; ++cc)
#pragma unroll
    for (int kt = 0; kt < 4; ++kt) {
      ushort4 pw;
#pragma unroll
      for (int r = 0; r < 4; ++r) {
        float p = __expf((accs[kt][cc][r] - mrow[cc]) * 0.125f);
        zrow[cc] += p;
        ((unsigned short*)&pw)[r] = f2bf(p);
      }
      *(ushort4*)&Pl[wid][cc * 16 + rl][kt * 16 + 4 * g] = pw;
    }
#pragma unroll
  for (int cc = 0; cc < 2; ++cc) {
    float z = zrow[cc];
    z += __shfl_xor(z, 16);
    z += __shfl_xor(z, 32);
    zrow[cc] = 1.0f / z;
  }

  f32x4 accp[4][2] = {};
#pragma unroll
  for (int ks = 0; ks < 2; ++ks) {
    short8 bp[2];
#pragma unroll
    for (int cc = 0; cc < 2; ++cc)
      bp[cc] = *(const short8*)&Pl[wid][cc * 16 + rl][ks * 32 + g * 8];
#pragma unroll
    for (int mt = 0; mt < 4; ++mt) {
      short8 av = *(const short8*)&Vt[mt * 16 + rl][wid * 32 + ks * 32 + g * 8];
#pragma unroll
      for (int cc = 0; cc < 2; ++cc)
        accp[mt][cc] = __builtin_amdgcn_mfma_f32_16x16x32_bf16(
            av, bp[cc], accp[mt][cc], 0, 0, 0);
    }
  }

#pragma unroll
  for (int mt = 0; mt < 4; ++mt)
#pragma unroll
    for (int cc = 0; cc < 2; ++cc) {
      int token = qb + cc * 16 + rl;
      if (token == 0) {
        *(ushort4*)&CTX[(size_t)(b * SS) * EE + h * DD + mt * 16 + 4 * g] = ushort4{0, 0, 0, 0};
        continue;
      }
      ushort4 o;
#pragma unroll
      for (int r = 0; r < 4; ++r)
        ((unsigned short*)&o)[r] = f2bf(accp[mt][cc][r] * zrow[cc]);
      *(ushort4*)&CTX[(size_t)(b * SS + token) * EE + h * DD + mt * 16 + 4 * g] = o;
    }
}

// ---------------- cls output rows: combine partials + GEMV (one launch) ----------------
__global__ void gemv_cls(const float* __restrict__ part,
                         const float* __restrict__ Wc,     // out_w_cls [1024][1024]
                         const float* __restrict__ bc,
                         float* __restrict__ out) {
  __shared__ float ctx[EE];
  __shared__ float u[HH][8];
  const int b = blockIdx.x >> 8;
  const int tid = threadIdx.x;
  const float* pb = part + (size_t)b * HH * 8 * 66;
  if (tid < HH) {
    const float* pp = pb + tid * 8 * 66;
    float M = -1e30f;
#pragma unroll
    for (int i = 0; i < 8; ++i) M = fmaxf(M, pp[i * 66]);
    float Z = 0.0f, w[8];
#pragma unroll
    for (int i = 0; i < 8; ++i) { w[i] = __expf(pp[i * 66] - M); Z += w[i] * pp[i * 66 + 1]; }
#pragma unroll
    for (int i = 0; i < 8; ++i) u[tid][i] = w[i] / Z;
  }
  __syncthreads();
  for (int k = tid; k < EE; k += 256) {
    int hh = k >> 6, d = k & 63;
    const float* pp = pb + hh * 8 * 66 + 2 + d;
    float a = 0.0f;
#pragma unroll
    for (int i = 0; i < 8; ++i) a += u[hh][i] * pp[i * 66];
    ctx[k] = a;
  }
  __syncthreads();
  int n = (blockIdx.x & 255) * 4 + (tid >> 6);
  int lane = tid & 63;
  const float* w = Wc + (size_t)n * EE;
  float s = 0.0f;
  for (int k = lane; k < EE; k += 64) s += ctx[k] * w[k];
  for (int o = 32; o; o >>= 1) s += __shfl_xor(s, o);
  if (lane == 0) out[(size_t)b * SS * EE + n] = s + bc[n];
}

extern "C" void kernel_launch(void* const* d_in, const int* in_sizes, int n_in,
                              void* d_out, int out_size, void* d_ws, size_t ws_size,
                              hipStream_t stream) {
  const float* hs        = (const float*)d_in[0];
  const float* in_w_cls  = (const float*)d_in[1];
  const float* in_b_cls  = (const float*)d_in[2];
  const float* out_w_cls = (const float*)d_in[3];
  const float* out_b_cls = (const float*)d_in[4];
  const float* in_w_loc  = (const float*)d_in[5];
  const float* in_b_loc  = (const float*)d_in[6];
  const float* out_w_loc = (const float*)d_in[7];
  const float* out_b_loc = (const float*)d_in[8];
  float* out = (float*)d_out;

  const int M = BB * SS;  // 4096
  char* ws = (char*)d_ws;
  size_t off = 0;
  auto alloc = [&](size_t bytes) { char* p = ws + off; off += (bytes + 255) & ~(size_t)255; return p; };
  unsigned short* Xbf  = (unsigned short*)alloc((size_t)M * EE * 2);
  unsigned short* W    = (unsigned short*)alloc((size_t)NY * EE * 2);
  unsigned short* Wout = (unsigned short*)alloc((size_t)EE * EE * 2);
  unsigned short* Yb   = (unsigned short*)alloc((size_t)M * NY * 2);
  unsigned short* CTX  = (unsigned short*)alloc((size_t)M * EE * 2);
  float* qcls = (float*)alloc(2 * EE * 4);
  float* part = (float*)alloc((size_t)BB * HH * 8 * 66 * 4);

  // 1) fused casts + q_cls GEMV
  cast_all<<<10752, 256, 0, stream>>>(
      hs, Xbf,
      in_w_cls + (size_t)EE * EE, W,
      in_w_loc, W + (size_t)2048 * EE,
      out_w_loc, Wout,
      in_w_cls, in_b_cls, qcls);

  // 2) merged projection GEMM (counted-vmcnt 8-phase, 256x320 tiles, 256 blocks)
  gemm8p<<<256, 512, 0, stream>>>(Xbf, W, in_b_cls, in_b_loc, Yb);

  // 3) fused attention (local MFMA + cls partials)
  attn_fused<<<dim3(24, HH, BB), 256, 0, stream>>>(qcls, Yb, part, CTX);

  // 4) local output projection (writes all rows of d_out; rows 0,2048 fixed next)
  {
    dim3 g3(M / 128, EE / 128);
    gemm_bt<0><<<g3, 256, 0, stream>>>(CTX, Wout, out_b_loc, out, M, EE, EE);
  }

  // 5) cls output rows (combine + GEMV fused)
  gemv_cls<<<512, 256, 0, stream>>>(part, out_w_cls, out_b_cls, out);
}